// Round 1
// baseline (539.325 us; speedup 1.0000x reference)
//
#include <hip/hip_runtime.h>

#define DM   1024
#define DFF  4096
#define NH   16
#define DKH  64
#define SEQ  2048
#define BATCH 2
#define ROWS (BATCH*SEQ)   // 4096

typedef __bf16 bf16x8 __attribute__((ext_vector_type(8)));
typedef float  f32x4  __attribute__((ext_vector_type(4)));

__device__ __forceinline__ unsigned short f2b(float f) {
    unsigned int u = __builtin_bit_cast(unsigned int, f);
    u += 0x7fffu + ((u >> 16) & 1u);   // RNE to bf16
    return (unsigned short)(u >> 16);
}
__device__ __forceinline__ float b2f(unsigned short u) {
    return __builtin_bit_cast(float, (unsigned int)u << 16);
}

// ---------------- prep: f32 -> bf16 ----------------
__global__ __launch_bounds__(256) void k_f32_to_bf16(const float* __restrict__ in,
                                                     unsigned short* __restrict__ out, int n4) {
    int i = blockIdx.x * 256 + threadIdx.x;
    if (i < n4) {
        float4 v = ((const float4*)in)[i];
        ushort4 u;
        u.x = f2b(v.x); u.y = f2b(v.y); u.z = f2b(v.z); u.w = f2b(v.w);
        ((ushort4*)out)[i] = u;
    }
}

// ---------------- prep: W[R][C] f32 -> WT[C][R] bf16 ----------------
__global__ __launch_bounds__(256) void k_transpose_bf16(const float* __restrict__ W,
                                                        unsigned short* __restrict__ WT,
                                                        int R, int C) {
    __shared__ float t[32][33];
    int c0 = blockIdx.x * 32, r0 = blockIdx.y * 32;
    int tx = threadIdx.x, ty = threadIdx.y;
#pragma unroll
    for (int i = 0; i < 4; i++) {
        int r = ty + i * 8;
        t[r][tx] = W[(size_t)(r0 + r) * C + c0 + tx];
    }
    __syncthreads();
#pragma unroll
    for (int i = 0; i < 4; i++) {
        int r = ty + i * 8;             // output row within tile => column c0+r of W
        WT[(size_t)(c0 + r) * R + r0 + tx] = f2b(t[tx][r]);
    }
}

// ---------------- GEMM: C[M][N] = act(A[M][K] @ BT[N][K]^T + bias) ----------------
// A, BT bf16 row-major. 128x128 tile, BK=64, 4 waves (2x2), 16x16x32 bf16 MFMA.
// LDS XOR-swizzled on 16B granules: granule' = g ^ (row&7)  (T2-style, reads ~2-way = free).
// BIASROW: bias indexed by output ROW (used when computing a transposed output).
template<bool OUTF32, bool RELU, bool BIASROW>
__global__ __launch_bounds__(256) void k_gemm_bt(const unsigned short* __restrict__ A,
                                                 const unsigned short* __restrict__ BT,
                                                 const float* __restrict__ bias,
                                                 void* __restrict__ Cout,
                                                 int M, int N, int K) {
    __shared__ unsigned short As[128][64] __attribute__((aligned(16)));
    __shared__ unsigned short Bs[128][64] __attribute__((aligned(16)));
    int tid = threadIdx.x;
    int w = tid >> 6, l = tid & 63;
    int wr = w >> 1, wc = w & 1;
    int l15 = l & 15, lg = l >> 4;
    int m0 = blockIdx.y * 128, n0 = blockIdx.x * 128;

    f32x4 acc[4][4] = {};

    int nk = K >> 6;
    for (int kt = 0; kt < nk; ++kt) {
        __syncthreads();
#pragma unroll
        for (int i = 0; i < 4; i++) {
            int e = i * 256 + tid;
            int row = e >> 3, g = e & 7;
            uint4 va = *(const uint4*)(A + (size_t)(m0 + row) * K + kt * 64 + g * 8);
            *(uint4*)&As[row][(g ^ (row & 7)) << 3] = va;
            uint4 vb = *(const uint4*)(BT + (size_t)(n0 + row) * K + kt * 64 + g * 8);
            *(uint4*)&Bs[row][(g ^ (row & 7)) << 3] = vb;
        }
        __syncthreads();
#pragma unroll
        for (int ks = 0; ks < 2; ++ks) {
            int glog = ks * 4 + lg;
            bf16x8 af[4], bfr[4];
#pragma unroll
            for (int mt = 0; mt < 4; ++mt) {
                int row = wr * 64 + mt * 16 + l15;
                af[mt] = *(const bf16x8*)&As[row][(glog ^ (row & 7)) << 3];
            }
#pragma unroll
            for (int nt = 0; nt < 4; ++nt) {
                int row = wc * 64 + nt * 16 + l15;
                bfr[nt] = *(const bf16x8*)&Bs[row][(glog ^ (row & 7)) << 3];
            }
#pragma unroll
            for (int mt = 0; mt < 4; ++mt)
#pragma unroll
                for (int nt = 0; nt < 4; ++nt)
                    acc[mt][nt] = __builtin_amdgcn_mfma_f32_16x16x32_bf16(af[mt], bfr[nt], acc[mt][nt], 0, 0, 0);
        }
    }
    // epilogue: C/D layout col = lane&15, row = 4*(lane>>4)+r  [m89]
    float browv[4][4];
    if (BIASROW) {
#pragma unroll
        for (int mt = 0; mt < 4; ++mt)
#pragma unroll
            for (int r = 0; r < 4; ++r)
                browv[mt][r] = bias[m0 + wr * 64 + mt * 16 + lg * 4 + r];
    }
#pragma unroll
    for (int nt = 0; nt < 4; ++nt) {
        int col = n0 + wc * 64 + nt * 16 + l15;
        float bv = BIASROW ? 0.f : bias[col];
#pragma unroll
        for (int mt = 0; mt < 4; ++mt) {
#pragma unroll
            for (int r = 0; r < 4; ++r) {
                int row = m0 + wr * 64 + mt * 16 + lg * 4 + r;
                float v = acc[mt][nt][r] + (BIASROW ? browv[mt][r] : bv);
                if (RELU) v = fmaxf(v, 0.f);
                if (OUTF32) ((float*)Cout)[(size_t)row * N + col] = v;
                else        ((unsigned short*)Cout)[(size_t)row * N + col] = f2b(v);
            }
        }
    }
}

// ---------------- flash attention (barrier-free) ----------------
// grid = (SEQ/64, BATCH*NH), block = 256 (4 waves). Each wave owns 16 q-rows.
// Q/K laid out (b, s, h*64+d) bf16 row-major (stride DM).
// VT laid out (h*64+d, b*SEQ+s) bf16 row-major (stride ROWS)  — produced by the V-proj GEMM.
// No LDS staging of K/V: fragments read directly from global (L1/L2-resident slabs),
// V frags prefetched before softmax. Only the wave-private P round-trip uses LDS.
__global__ __launch_bounds__(256) void k_attn(const unsigned short* __restrict__ Q,
                                              const unsigned short* __restrict__ Kb,
                                              const unsigned short* __restrict__ VT,
                                              unsigned short* __restrict__ O) {
    __shared__ unsigned short ps[4][16 * 64] __attribute__((aligned(16)));

    int tid = threadIdx.x;
    int w = tid >> 6, l = tid & 63;
    int l15 = l & 15, lg = l >> 4;

    // bijective XCD swizzle: the 32 q-blocks sharing one (b,h) K/V slab land on one XCD
    int bid = blockIdx.y * gridDim.x + blockIdx.x;          // 0..1023
    int bh = (bid & 7) * 4 + ((bid >> 3) & 3);              // 8 XCDs x 4 bh each
    int qt = bid >> 5;                                      // 0..31
    int b = bh >> 4, h = bh & 15;
    int row0 = qt * 64;

    const unsigned short* qg  = Q  + (size_t)b * SEQ * DM + h * DKH;
    const unsigned short* kg  = Kb + (size_t)b * SEQ * DM + h * DKH;
    const unsigned short* vtg = VT + (size_t)(h * DKH) * ROWS + (size_t)b * SEQ;

    // Q fragment, pre-scaled by 1/sqrt(dk) = 0.125 (exact pow-2 scale in bf16)
    bf16x8 aq[2];
    {
        int qrow = row0 + w * 16 + l15;
#pragma unroll
        for (int ksi = 0; ksi < 2; ksi++) {
            bf16x8 v = *(const bf16x8*)(qg + (size_t)qrow * DM + (ksi * 4 + lg) * 8);
            const unsigned short* pu = (const unsigned short*)&v;
            bf16x8 rsc;
            unsigned short* pr = (unsigned short*)&rsc;
#pragma unroll
            for (int j = 0; j < 8; j++) pr[j] = f2b(b2f(pu[j]) * 0.125f);
            aq[ksi] = rsc;
        }
    }

    f32x4 o[4] = {};
    float mrun[4], lrun[4];
#pragma unroll
    for (int r = 0; r < 4; r++) { mrun[r] = -__builtin_inff(); lrun[r] = 0.f; }

    unsigned short* pw = ps[w];

    for (int kt = 0; kt < SEQ / 64; ++kt) {
        const unsigned short* kbase = kg + (size_t)(kt * 64) * DM;

        // prefetch V^T fragments — independent of everything, land during softmax
        bf16x8 vf[2][4];
#pragma unroll
        for (int ksi = 0; ksi < 2; ksi++) {
            int glog = ksi * 4 + lg;
#pragma unroll
            for (int nt = 0; nt < 4; nt++)
                vf[ksi][nt] = *(const bf16x8*)(vtg + (size_t)(nt * 16 + l15) * ROWS + kt * 64 + glog * 8);
        }

        // S = (q/8) @ k^T   (16 rows x 64 keys per wave); K frags direct from global
        f32x4 s[4] = {};
#pragma unroll
        for (int ksi = 0; ksi < 2; ksi++) {
            int glog = ksi * 4 + lg;
#pragma unroll
            for (int nt = 0; nt < 4; nt++) {
                bf16x8 bk = *(const bf16x8*)(kbase + (size_t)(nt * 16 + l15) * DM + glog * 8);
                s[nt] = __builtin_amdgcn_mfma_f32_16x16x32_bf16(aq[ksi], bk, s[nt], 0, 0, 0);
            }
        }

        // online softmax: rows = 4*lg + r, spread across the 16 lanes l&15
        float mt_[4];
#pragma unroll
        for (int r = 0; r < 4; r++)
            mt_[r] = fmaxf(fmaxf(s[0][r], s[1][r]), fmaxf(s[2][r], s[3][r]));
#pragma unroll
        for (int msk = 1; msk < 16; msk <<= 1)
#pragma unroll
            for (int r = 0; r < 4; r++) mt_[r] = fmaxf(mt_[r], __shfl_xor(mt_[r], msk));

        float al[4], psum[4];
#pragma unroll
        for (int r = 0; r < 4; r++) {
            float nm = fmaxf(mrun[r], mt_[r]);
            al[r] = __expf(mrun[r] - nm);
            mrun[r] = nm;
            psum[r] = 0.f;
        }
        float p[4][4];
#pragma unroll
        for (int nt = 0; nt < 4; nt++)
#pragma unroll
            for (int r = 0; r < 4; r++) {
                float pv_ = __expf(s[nt][r] - mrun[r]);
                p[nt][r] = pv_;
                psum[r] += pv_;
            }
#pragma unroll
        for (int msk = 1; msk < 16; msk <<= 1)
#pragma unroll
            for (int r = 0; r < 4; r++) psum[r] += __shfl_xor(psum[r], msk);
#pragma unroll
        for (int r = 0; r < 4; r++) lrun[r] = lrun[r] * al[r] + psum[r];
#pragma unroll
        for (int nt = 0; nt < 4; nt++)
#pragma unroll
            for (int r = 0; r < 4; r++) o[nt][r] *= al[r];

        // write P (wave-private region, swizzled), then read back as MFMA A-frag
#pragma unroll
        for (int nt = 0; nt < 4; nt++)
#pragma unroll
            for (int r = 0; r < 4; r++) {
                int R = lg * 4 + r;
                int c = nt * 16 + l15;
                pw[R * 64 + (((c >> 3) ^ (R & 7)) << 3) + (c & 7)] = f2b(p[nt][r]);
            }
        asm volatile("s_waitcnt lgkmcnt(0)" ::: "memory");

        // O += P @ V  (V frags already in registers)
#pragma unroll
        for (int ksi = 0; ksi < 2; ksi++) {
            int glog = ksi * 4 + lg;
            bf16x8 ap = *(const bf16x8*)&pw[l15 * 64 + ((glog ^ (l15 & 7)) << 3)];
#pragma unroll
            for (int nt = 0; nt < 4; nt++)
                o[nt] = __builtin_amdgcn_mfma_f32_16x16x32_bf16(ap, vf[ksi][nt], o[nt], 0, 0, 0);
        }
    }

    float rinv[4];
#pragma unroll
    for (int r = 0; r < 4; r++) rinv[r] = 1.f / lrun[r];
    unsigned short* og = O + (size_t)b * SEQ * DM + h * DKH;
#pragma unroll
    for (int nt = 0; nt < 4; nt++) {
        int d = nt * 16 + l15;
#pragma unroll
        for (int r = 0; r < 4; r++) {
            int srow = row0 + w * 16 + lg * 4 + r;
            og[(size_t)srow * DM + d] = f2b(o[nt][r] * rinv[r]);
        }
    }
}

// ---------------- fused residual add + LayerNorm ----------------
template<bool WB16>
__global__ __launch_bounds__(256) void k_add_ln(const float* __restrict__ a,
                                                const float* __restrict__ b,
                                                const float* __restrict__ gamma,
                                                const float* __restrict__ beta,
                                                float* __restrict__ outf,
                                                unsigned short* __restrict__ outb) {
    __shared__ float red[8];
    int row = blockIdx.x, tid = threadIdx.x;
    float4 va = ((const float4*)(a + (size_t)row * DM))[tid];
    float4 vb = ((const float4*)(b + (size_t)row * DM))[tid];
    float4 v;
    v.x = va.x + vb.x; v.y = va.y + vb.y; v.z = va.z + vb.z; v.w = va.w + vb.w;
    float s = v.x + v.y + v.z + v.w;
    float q = v.x * v.x + v.y * v.y + v.z * v.z + v.w * v.w;
#pragma unroll
    for (int m = 1; m < 64; m <<= 1) { s += __shfl_xor(s, m); q += __shfl_xor(q, m); }
    if ((tid & 63) == 0) { red[tid >> 6] = s; red[4 + (tid >> 6)] = q; }
    __syncthreads();
    float tot  = red[0] + red[1] + red[2] + red[3];
    float totq = red[4] + red[5] + red[6] + red[7];
    float mu = tot * (1.f / DM);
    float var = totq * (1.f / DM) - mu * mu;
    float rs = rsqrtf(var + 1e-5f);
    float4 g  = ((const float4*)gamma)[tid];
    float4 be = ((const float4*)beta)[tid];
    float4 y;
    y.x = (v.x - mu) * rs * g.x + be.x;
    y.y = (v.y - mu) * rs * g.y + be.y;
    y.z = (v.z - mu) * rs * g.z + be.z;
    y.w = (v.w - mu) * rs * g.w + be.w;
    ((float4*)(outf + (size_t)row * DM))[tid] = y;
    if (WB16) {
        ushort4 u;
        u.x = f2b(y.x); u.y = f2b(y.y); u.z = f2b(y.z); u.w = f2b(y.w);
        ((ushort4*)(outb + (size_t)row * DM))[tid] = u;
    }
}

// ---------------- orchestration ----------------
extern "C" void kernel_launch(void* const* d_in, const int* in_sizes, int n_in,
                              void* d_out, int out_size, void* d_ws, size_t ws_size,
                              hipStream_t stream) {
    const float* x   = (const float*)d_in[0];
    const float* Wq  = (const float*)d_in[1];
    const float* bq  = (const float*)d_in[2];
    const float* Wk  = (const float*)d_in[3];
    const float* bk  = (const float*)d_in[4];
    const float* Wv  = (const float*)d_in[5];
    const float* bv  = (const float*)d_in[6];
    const float* Wo  = (const float*)d_in[7];
    const float* bo  = (const float*)d_in[8];
    const float* W1  = (const float*)d_in[9];
    const float* b1  = (const float*)d_in[10];
    const float* W2  = (const float*)d_in[11];
    const float* b2  = (const float*)d_in[12];
    const float* g1  = (const float*)d_in[13];
    const float* be1 = (const float*)d_in[14];
    const float* g2  = (const float*)d_in[15];
    const float* be2 = (const float*)d_in[16];

    char* ws = (char*)d_ws;
    const size_t MB = 1u << 20;
    unsigned short* xb    = (unsigned short*)(ws + 0);        // 8MB; reused as attn_out
    unsigned short* WqT   = (unsigned short*)(ws + 8 * MB);   // 2MB each
    unsigned short* WkT   = (unsigned short*)(ws + 10 * MB);
    unsigned short* WvT   = (unsigned short*)(ws + 12 * MB);
    unsigned short* WoT   = (unsigned short*)(ws + 14 * MB);
    unsigned short* W1T   = (unsigned short*)(ws + 16 * MB);  // 8MB
    unsigned short* W2T   = (unsigned short*)(ws + 24 * MB);  // 8MB
    unsigned short* qb    = (unsigned short*)(ws + 32 * MB);  // 8MB
    unsigned short* kb    = (unsigned short*)(ws + 40 * MB);  // 8MB
    unsigned short* vT    = (unsigned short*)(ws + 48 * MB);  // 8MB: V^T (d_all, b*S+s)
    float*          scrf  = (float*)(ws + 56 * MB);           // 16MB: attn_proj, then ff2
    float*          resid = (float*)(ws + 72 * MB);           // 16MB
    unsigned short* residb= (unsigned short*)(ws + 88 * MB);  // 8MB
    unsigned short* h1    = (unsigned short*)(ws + 96 * MB);  // 32MB

    dim3 blk(256);
    dim3 tb(32, 8);

    k_f32_to_bf16<<<(ROWS * DM / 4 + 255) / 256, blk, 0, stream>>>(x, xb, ROWS * DM / 4);
    k_transpose_bf16<<<dim3(DM / 32, DM / 32), tb, 0, stream>>>(Wq, WqT, DM, DM);
    k_transpose_bf16<<<dim3(DM / 32, DM / 32), tb, 0, stream>>>(Wk, WkT, DM, DM);
    k_transpose_bf16<<<dim3(DM / 32, DM / 32), tb, 0, stream>>>(Wv, WvT, DM, DM);
    k_transpose_bf16<<<dim3(DM / 32, DM / 32), tb, 0, stream>>>(Wo, WoT, DM, DM);
    k_transpose_bf16<<<dim3(DFF / 32, DM / 32), tb, 0, stream>>>(W1, W1T, DM, DFF);
    k_transpose_bf16<<<dim3(DM / 32, DFF / 32), tb, 0, stream>>>(W2, W2T, DFF, DM);

    k_gemm_bt<false, false, false><<<dim3(DM / 128, ROWS / 128), blk, 0, stream>>>(xb, WqT, bq, qb, ROWS, DM, DM);
    k_gemm_bt<false, false, false><<<dim3(DM / 128, ROWS / 128), blk, 0, stream>>>(xb, WkT, bk, kb, ROWS, DM, DM);
    // V^T = WvT @ xb^T  (C[d_all][b*S+s] = (x@Wv+bv)^T), bias per output row
    k_gemm_bt<false, false, true><<<dim3(ROWS / 128, DM / 128), blk, 0, stream>>>(WvT, xb, bv, vT, DM, ROWS, DM);

    k_attn<<<dim3(SEQ / 64, BATCH * NH), blk, 0, stream>>>(qb, kb, vT, xb);

    k_gemm_bt<true, false, false><<<dim3(DM / 128, ROWS / 128), blk, 0, stream>>>(xb, WoT, bo, scrf, ROWS, DM, DM);
    k_add_ln<true><<<ROWS, blk, 0, stream>>>(x, scrf, g1, be1, resid, residb);

    k_gemm_bt<false, true, false><<<dim3(DFF / 128, ROWS / 128), blk, 0, stream>>>(residb, W1T, b1, h1, ROWS, DFF, DM);
    k_gemm_bt<true, false, false><<<dim3(DM / 128, ROWS / 128), blk, 0, stream>>>(h1, W2T, b2, scrf, ROWS, DM, DFF);
    k_add_ln<false><<<ROWS, blk, 0, stream>>>(resid, scrf, g2, be2, (float*)d_out, nullptr);
}

// Round 2
// 372.286 us; speedup vs baseline: 1.4487x; 1.4487x over previous
//
#include <hip/hip_runtime.h>

#define DM   1024
#define DFF  4096
#define NH   16
#define DKH  64
#define SEQ  2048
#define BATCH 2
#define ROWS (BATCH*SEQ)   // 4096

typedef __bf16 bf16x8 __attribute__((ext_vector_type(8)));
typedef float  f32x4  __attribute__((ext_vector_type(4)));

__device__ __forceinline__ unsigned short f2b(float f) {
    unsigned int u = __builtin_bit_cast(unsigned int, f);
    u += 0x7fffu + ((u >> 16) & 1u);   // RNE to bf16
    return (unsigned short)(u >> 16);
}
__device__ __forceinline__ float b2f(unsigned short u) {
    return __builtin_bit_cast(float, (unsigned int)u << 16);
}

// ---------------- prep: f32 -> bf16 ----------------
__global__ __launch_bounds__(256) void k_f32_to_bf16(const float* __restrict__ in,
                                                     unsigned short* __restrict__ out, int n4) {
    int i = blockIdx.x * 256 + threadIdx.x;
    if (i < n4) {
        float4 v = ((const float4*)in)[i];
        ushort4 u;
        u.x = f2b(v.x); u.y = f2b(v.y); u.z = f2b(v.z); u.w = f2b(v.w);
        ((ushort4*)out)[i] = u;
    }
}

// ---------------- prep: W[R][C] f32 -> WT[C][R] bf16 ----------------
__global__ __launch_bounds__(256) void k_transpose_bf16(const float* __restrict__ W,
                                                        unsigned short* __restrict__ WT,
                                                        int R, int C) {
    __shared__ float t[32][33];
    int c0 = blockIdx.x * 32, r0 = blockIdx.y * 32;
    int tx = threadIdx.x, ty = threadIdx.y;
#pragma unroll
    for (int i = 0; i < 4; i++) {
        int r = ty + i * 8;
        t[r][tx] = W[(size_t)(r0 + r) * C + c0 + tx];
    }
    __syncthreads();
#pragma unroll
    for (int i = 0; i < 4; i++) {
        int r = ty + i * 8;             // output row within tile => column c0+r of W
        WT[(size_t)(c0 + r) * R + r0 + tx] = f2b(t[tx][r]);
    }
}

// ---------------- GEMM: C[M][N] = act(A[M][K] @ BT[N][K]^T + bias) ----------------
// A, BT bf16 row-major. 128x128 tile, BK=64, 4 waves (2x2), 16x16x32 bf16 MFMA.
// LDS XOR-swizzled on 16B granules: granule' = g ^ (row&7)  (T2-style, reads ~2-way = free).
// BIASROW: bias indexed by output ROW (used when computing a transposed output).
template<bool OUTF32, bool RELU, bool BIASROW>
__global__ __launch_bounds__(256) void k_gemm_bt(const unsigned short* __restrict__ A,
                                                 const unsigned short* __restrict__ BT,
                                                 const float* __restrict__ bias,
                                                 void* __restrict__ Cout,
                                                 int M, int N, int K) {
    __shared__ unsigned short As[128][64] __attribute__((aligned(16)));
    __shared__ unsigned short Bs[128][64] __attribute__((aligned(16)));
    int tid = threadIdx.x;
    int w = tid >> 6, l = tid & 63;
    int wr = w >> 1, wc = w & 1;
    int l15 = l & 15, lg = l >> 4;
    int m0 = blockIdx.y * 128, n0 = blockIdx.x * 128;

    f32x4 acc[4][4] = {};

    int nk = K >> 6;
    for (int kt = 0; kt < nk; ++kt) {
        __syncthreads();
#pragma unroll
        for (int i = 0; i < 4; i++) {
            int e = i * 256 + tid;
            int row = e >> 3, g = e & 7;
            uint4 va = *(const uint4*)(A + (size_t)(m0 + row) * K + kt * 64 + g * 8);
            *(uint4*)&As[row][(g ^ (row & 7)) << 3] = va;
            uint4 vb = *(const uint4*)(BT + (size_t)(n0 + row) * K + kt * 64 + g * 8);
            *(uint4*)&Bs[row][(g ^ (row & 7)) << 3] = vb;
        }
        __syncthreads();
#pragma unroll
        for (int ks = 0; ks < 2; ++ks) {
            int glog = ks * 4 + lg;
            bf16x8 af[4], bfr[4];
#pragma unroll
            for (int mt = 0; mt < 4; ++mt) {
                int row = wr * 64 + mt * 16 + l15;
                af[mt] = *(const bf16x8*)&As[row][(glog ^ (row & 7)) << 3];
            }
#pragma unroll
            for (int nt = 0; nt < 4; ++nt) {
                int row = wc * 64 + nt * 16 + l15;
                bfr[nt] = *(const bf16x8*)&Bs[row][(glog ^ (row & 7)) << 3];
            }
#pragma unroll
            for (int mt = 0; mt < 4; ++mt)
#pragma unroll
                for (int nt = 0; nt < 4; ++nt)
                    acc[mt][nt] = __builtin_amdgcn_mfma_f32_16x16x32_bf16(af[mt], bfr[nt], acc[mt][nt], 0, 0, 0);
        }
    }
    // epilogue: C/D layout col = lane&15, row = 4*(lane>>4)+r  [m89]
    float browv[4][4];
    if (BIASROW) {
#pragma unroll
        for (int mt = 0; mt < 4; ++mt)
#pragma unroll
            for (int r = 0; r < 4; ++r)
                browv[mt][r] = bias[m0 + wr * 64 + mt * 16 + lg * 4 + r];
    }
#pragma unroll
    for (int nt = 0; nt < 4; ++nt) {
        int col = n0 + wc * 64 + nt * 16 + l15;
        float bv = BIASROW ? 0.f : bias[col];
#pragma unroll
        for (int mt = 0; mt < 4; ++mt) {
#pragma unroll
            for (int r = 0; r < 4; ++r) {
                int row = m0 + wr * 64 + mt * 16 + lg * 4 + r;
                float v = acc[mt][nt][r] + (BIASROW ? browv[mt][r] : bv);
                if (RELU) v = fmaxf(v, 0.f);
                if (OUTF32) ((float*)Cout)[(size_t)row * N + col] = v;
                else        ((unsigned short*)Cout)[(size_t)row * N + col] = f2b(v);
            }
        }
    }
}

// ---------------- flash attention ----------------
// grid = (SEQ/64, BATCH*NH) flattened+XCD-swizzled, block = 256 (4 waves).
// Each wave owns 16 q-rows. Q/K laid out (b, s, h*64+d) bf16 (stride DM).
// VT laid out (h*64+d, b*SEQ+s) bf16 (stride ROWS) — produced by the V-proj GEMM,
// so V staging is a straight swizzled copy (no in-kernel transpose scatter).
// Pipeline: register-double-buffered staging, ONE barrier per key-tile:
//   write regs(tile kt)->LDS[cur]; issue loads(kt+1)->regs; barrier; compute LDS[cur].
__global__ __launch_bounds__(256) void k_attn(const unsigned short* __restrict__ Q,
                                              const unsigned short* __restrict__ Kb,
                                              const unsigned short* __restrict__ VT,
                                              unsigned short* __restrict__ O) {
    __shared__ unsigned short ks[2][64][64] __attribute__((aligned(16)));
    __shared__ unsigned short vs[2][64][64] __attribute__((aligned(16)));
    __shared__ unsigned short ps[4][16 * 64] __attribute__((aligned(16)));

    int tid = threadIdx.x;
    int w = tid >> 6, l = tid & 63;
    int l15 = l & 15, lg = l >> 4;

    // bijective XCD swizzle: the 32 q-blocks sharing one (b,h) K/V slab land on one XCD
    int bid = blockIdx.y * gridDim.x + blockIdx.x;          // 0..1023
    int bh = (bid & 7) * 4 + ((bid >> 3) & 3);              // 8 XCDs x 4 bh each
    int qt = bid >> 5;                                      // 0..31
    int b = bh >> 4, h = bh & 15;
    int row0 = qt * 64;

    const unsigned short* qg  = Q  + (size_t)b * SEQ * DM + h * DKH;
    const unsigned short* kg  = Kb + (size_t)b * SEQ * DM + h * DKH;
    const unsigned short* vtg = VT + (size_t)(h * DKH) * ROWS + (size_t)b * SEQ;

    // staging coords: chunk i covers rows i*32 + (tid>>3), granule tid&7
    int srow = tid >> 3, sg = tid & 7;
    int sswz = (sg ^ (srow & 7)) << 3;   // same for both chunks (rows differ by 32)

    // Q fragment, pre-scaled by 1/sqrt(dk) = 0.125 (exact pow-2 scale in bf16)
    bf16x8 aq[2];
    {
        int qrow = row0 + w * 16 + l15;
#pragma unroll
        for (int ksi = 0; ksi < 2; ksi++) {
            bf16x8 v = *(const bf16x8*)(qg + (size_t)qrow * DM + (ksi * 4 + lg) * 8);
            const unsigned short* pu = (const unsigned short*)&v;
            bf16x8 rsc;
            unsigned short* pr = (unsigned short*)&rsc;
#pragma unroll
            for (int j = 0; j < 8; j++) pr[j] = f2b(b2f(pu[j]) * 0.125f);
            aq[ksi] = rsc;
        }
    }

    f32x4 o[4] = {};
    float mrun[4], lrun[4];
#pragma unroll
    for (int r = 0; r < 4; r++) { mrun[r] = -__builtin_inff(); lrun[r] = 0.f; }

    unsigned short* pw = ps[w];

    // prologue: issue loads for tile 0
    uint4 kr0, kr1, vr0, vr1;
    kr0 = *(const uint4*)(kg + (size_t)(srow) * DM + sg * 8);
    kr1 = *(const uint4*)(kg + (size_t)(32 + srow) * DM + sg * 8);
    vr0 = *(const uint4*)(vtg + (size_t)(srow) * ROWS + sg * 8);
    vr1 = *(const uint4*)(vtg + (size_t)(32 + srow) * ROWS + sg * 8);

    int cur = 0;
    for (int kt = 0; kt < SEQ / 64; ++kt) {
        // write prefetched tile into LDS[cur] (compiler inserts vmcnt wait)
        *(uint4*)&ks[cur][srow][sswz]      = kr0;
        *(uint4*)&ks[cur][32 + srow][sswz] = kr1;
        *(uint4*)&vs[cur][srow][sswz]      = vr0;
        *(uint4*)&vs[cur][32 + srow][sswz] = vr1;

        // issue loads for tile kt+1 (land during compute below)
        if (kt + 1 < SEQ / 64) {
            const unsigned short* kb2 = kg + (size_t)((kt + 1) * 64) * DM;
            kr0 = *(const uint4*)(kb2 + (size_t)(srow) * DM + sg * 8);
            kr1 = *(const uint4*)(kb2 + (size_t)(32 + srow) * DM + sg * 8);
            vr0 = *(const uint4*)(vtg + (size_t)(srow) * ROWS + (kt + 1) * 64 + sg * 8);
            vr1 = *(const uint4*)(vtg + (size_t)(32 + srow) * ROWS + (kt + 1) * 64 + sg * 8);
        }

        __syncthreads();

        // S = (q/8) @ k^T   (16 rows x 64 keys per wave)
        f32x4 s[4] = {};
        __builtin_amdgcn_s_setprio(1);
#pragma unroll
        for (int ksi = 0; ksi < 2; ksi++) {
            int glog = ksi * 4 + lg;
#pragma unroll
            for (int nt = 0; nt < 4; nt++) {
                int row = nt * 16 + l15;
                bf16x8 bk = *(const bf16x8*)&ks[cur][row][(glog ^ (row & 7)) << 3];
                s[nt] = __builtin_amdgcn_mfma_f32_16x16x32_bf16(aq[ksi], bk, s[nt], 0, 0, 0);
            }
        }
        __builtin_amdgcn_s_setprio(0);

        // online softmax: rows = 4*lg + r, spread across the 16 lanes l&15
        float mt_[4];
#pragma unroll
        for (int r = 0; r < 4; r++)
            mt_[r] = fmaxf(fmaxf(s[0][r], s[1][r]), fmaxf(s[2][r], s[3][r]));
#pragma unroll
        for (int msk = 1; msk < 16; msk <<= 1)
#pragma unroll
            for (int r = 0; r < 4; r++) mt_[r] = fmaxf(mt_[r], __shfl_xor(mt_[r], msk));

        float al[4], psum[4];
#pragma unroll
        for (int r = 0; r < 4; r++) {
            float nm = fmaxf(mrun[r], mt_[r]);
            al[r] = __expf(mrun[r] - nm);
            mrun[r] = nm;
            psum[r] = 0.f;
        }
        float p[4][4];
#pragma unroll
        for (int nt = 0; nt < 4; nt++)
#pragma unroll
            for (int r = 0; r < 4; r++) {
                float pv_ = __expf(s[nt][r] - mrun[r]);
                p[nt][r] = pv_;
                psum[r] += pv_;
            }
#pragma unroll
        for (int msk = 1; msk < 16; msk <<= 1)
#pragma unroll
            for (int r = 0; r < 4; r++) psum[r] += __shfl_xor(psum[r], msk);
#pragma unroll
        for (int r = 0; r < 4; r++) lrun[r] = lrun[r] * al[r] + psum[r];
#pragma unroll
        for (int nt = 0; nt < 4; nt++)
#pragma unroll
            for (int r = 0; r < 4; r++) o[nt][r] *= al[r];

        // write P (wave-private region, swizzled), then read back as MFMA A-frag
#pragma unroll
        for (int nt = 0; nt < 4; nt++)
#pragma unroll
            for (int r = 0; r < 4; r++) {
                int R = lg * 4 + r;
                int c = nt * 16 + l15;
                pw[R * 64 + (((c >> 3) ^ (R & 7)) << 3) + (c & 7)] = f2b(p[nt][r]);
            }
        asm volatile("s_waitcnt lgkmcnt(0)" ::: "memory");

        // O += P @ V
        __builtin_amdgcn_s_setprio(1);
#pragma unroll
        for (int ksi = 0; ksi < 2; ksi++) {
            int glog = ksi * 4 + lg;
            bf16x8 ap = *(const bf16x8*)&pw[l15 * 64 + ((glog ^ (l15 & 7)) << 3)];
#pragma unroll
            for (int nt = 0; nt < 4; nt++) {
                int row = nt * 16 + l15;   // row = d
                bf16x8 bv = *(const bf16x8*)&vs[cur][row][(glog ^ (row & 7)) << 3];
                o[nt] = __builtin_amdgcn_mfma_f32_16x16x32_bf16(ap, bv, o[nt], 0, 0, 0);
            }
        }
        __builtin_amdgcn_s_setprio(0);

        cur ^= 1;
    }

    float rinv[4];
#pragma unroll
    for (int r = 0; r < 4; r++) rinv[r] = 1.f / lrun[r];
    unsigned short* og = O + (size_t)b * SEQ * DM + h * DKH;
#pragma unroll
    for (int nt = 0; nt < 4; nt++) {
        int d = nt * 16 + l15;
#pragma unroll
        for (int r = 0; r < 4; r++) {
            int srow_ = row0 + w * 16 + lg * 4 + r;
            og[(size_t)srow_ * DM + d] = f2b(o[nt][r] * rinv[r]);
        }
    }
}

// ---------------- fused residual add + LayerNorm ----------------
template<bool WB16>
__global__ __launch_bounds__(256) void k_add_ln(const float* __restrict__ a,
                                                const float* __restrict__ b,
                                                const float* __restrict__ gamma,
                                                const float* __restrict__ beta,
                                                float* __restrict__ outf,
                                                unsigned short* __restrict__ outb) {
    __shared__ float red[8];
    int row = blockIdx.x, tid = threadIdx.x;
    float4 va = ((const float4*)(a + (size_t)row * DM))[tid];
    float4 vb = ((const float4*)(b + (size_t)row * DM))[tid];
    float4 v;
    v.x = va.x + vb.x; v.y = va.y + vb.y; v.z = va.z + vb.z; v.w = va.w + vb.w;
    float s = v.x + v.y + v.z + v.w;
    float q = v.x * v.x + v.y * v.y + v.z * v.z + v.w * v.w;
#pragma unroll
    for (int m = 1; m < 64; m <<= 1) { s += __shfl_xor(s, m); q += __shfl_xor(q, m); }
    if ((tid & 63) == 0) { red[tid >> 6] = s; red[4 + (tid >> 6)] = q; }
    __syncthreads();
    float tot  = red[0] + red[1] + red[2] + red[3];
    float totq = red[4] + red[5] + red[6] + red[7];
    float mu = tot * (1.f / DM);
    float var = totq * (1.f / DM) - mu * mu;
    float rs = rsqrtf(var + 1e-5f);
    float4 g  = ((const float4*)gamma)[tid];
    float4 be = ((const float4*)beta)[tid];
    float4 y;
    y.x = (v.x - mu) * rs * g.x + be.x;
    y.y = (v.y - mu) * rs * g.y + be.y;
    y.z = (v.z - mu) * rs * g.z + be.z;
    y.w = (v.w - mu) * rs * g.w + be.w;
    ((float4*)(outf + (size_t)row * DM))[tid] = y;
    if (WB16) {
        ushort4 u;
        u.x = f2b(y.x); u.y = f2b(y.y); u.z = f2b(y.z); u.w = f2b(y.w);
        ((ushort4*)(outb + (size_t)row * DM))[tid] = u;
    }
}

// ---------------- orchestration ----------------
extern "C" void kernel_launch(void* const* d_in, const int* in_sizes, int n_in,
                              void* d_out, int out_size, void* d_ws, size_t ws_size,
                              hipStream_t stream) {
    const float* x   = (const float*)d_in[0];
    const float* Wq  = (const float*)d_in[1];
    const float* bq  = (const float*)d_in[2];
    const float* Wk  = (const float*)d_in[3];
    const float* bk  = (const float*)d_in[4];
    const float* Wv  = (const float*)d_in[5];
    const float* bv  = (const float*)d_in[6];
    const float* Wo  = (const float*)d_in[7];
    const float* bo  = (const float*)d_in[8];
    const float* W1  = (const float*)d_in[9];
    const float* b1  = (const float*)d_in[10];
    const float* W2  = (const float*)d_in[11];
    const float* b2  = (const float*)d_in[12];
    const float* g1  = (const float*)d_in[13];
    const float* be1 = (const float*)d_in[14];
    const float* g2  = (const float*)d_in[15];
    const float* be2 = (const float*)d_in[16];

    char* ws = (char*)d_ws;
    const size_t MB = 1u << 20;
    unsigned short* xb    = (unsigned short*)(ws + 0);        // 8MB; reused as attn_out
    unsigned short* WqT   = (unsigned short*)(ws + 8 * MB);   // 2MB each
    unsigned short* WkT   = (unsigned short*)(ws + 10 * MB);
    unsigned short* WvT   = (unsigned short*)(ws + 12 * MB);
    unsigned short* WoT   = (unsigned short*)(ws + 14 * MB);
    unsigned short* W1T   = (unsigned short*)(ws + 16 * MB);  // 8MB
    unsigned short* W2T   = (unsigned short*)(ws + 24 * MB);  // 8MB
    unsigned short* qb    = (unsigned short*)(ws + 32 * MB);  // 8MB
    unsigned short* kb    = (unsigned short*)(ws + 40 * MB);  // 8MB
    unsigned short* vT    = (unsigned short*)(ws + 48 * MB);  // 8MB: V^T (d_all, b*S+s)
    float*          scrf  = (float*)(ws + 56 * MB);           // 16MB: attn_proj, then ff2
    float*          resid = (float*)(ws + 72 * MB);           // 16MB
    unsigned short* residb= (unsigned short*)(ws + 88 * MB);  // 8MB
    unsigned short* h1    = (unsigned short*)(ws + 96 * MB);  // 32MB

    dim3 blk(256);
    dim3 tb(32, 8);

    k_f32_to_bf16<<<(ROWS * DM / 4 + 255) / 256, blk, 0, stream>>>(x, xb, ROWS * DM / 4);
    k_transpose_bf16<<<dim3(DM / 32, DM / 32), tb, 0, stream>>>(Wq, WqT, DM, DM);
    k_transpose_bf16<<<dim3(DM / 32, DM / 32), tb, 0, stream>>>(Wk, WkT, DM, DM);
    k_transpose_bf16<<<dim3(DM / 32, DM / 32), tb, 0, stream>>>(Wv, WvT, DM, DM);
    k_transpose_bf16<<<dim3(DM / 32, DM / 32), tb, 0, stream>>>(Wo, WoT, DM, DM);
    k_transpose_bf16<<<dim3(DFF / 32, DM / 32), tb, 0, stream>>>(W1, W1T, DM, DFF);
    k_transpose_bf16<<<dim3(DM / 32, DFF / 32), tb, 0, stream>>>(W2, W2T, DFF, DM);

    k_gemm_bt<false, false, false><<<dim3(DM / 128, ROWS / 128), blk, 0, stream>>>(xb, WqT, bq, qb, ROWS, DM, DM);
    k_gemm_bt<false, false, false><<<dim3(DM / 128, ROWS / 128), blk, 0, stream>>>(xb, WkT, bk, kb, ROWS, DM, DM);
    // V^T = WvT @ xb^T  (C[d_all][b*S+s] = (x@Wv+bv)^T), bias per output row
    k_gemm_bt<false, false, true><<<dim3(ROWS / 128, DM / 128), blk, 0, stream>>>(WvT, xb, bv, vT, DM, ROWS, DM);

    k_attn<<<dim3(SEQ / 64, BATCH * NH), blk, 0, stream>>>(qb, kb, vT, xb);

    k_gemm_bt<true, false, false><<<dim3(DM / 128, ROWS / 128), blk, 0, stream>>>(xb, WoT, bo, scrf, ROWS, DM, DM);
    k_add_ln<true><<<ROWS, blk, 0, stream>>>(x, scrf, g1, be1, resid, residb);

    k_gemm_bt<false, true, false><<<dim3(DFF / 128, ROWS / 128), blk, 0, stream>>>(residb, W1T, b1, h1, ROWS, DFF, DM);
    k_gemm_bt<true, false, false><<<dim3(DM / 128, ROWS / 128), blk, 0, stream>>>(h1, W2T, b2, scrf, ROWS, DM, DFF);
    k_add_ln<false><<<ROWS, blk, 0, stream>>>(resid, scrf, g2, be2, (float*)d_out, nullptr);
}

// Round 3
// 365.365 us; speedup vs baseline: 1.4761x; 1.0189x over previous
//
#include <hip/hip_runtime.h>

#define DM   1024
#define DFF  4096
#define NH   16
#define DKH  64
#define SEQ  2048
#define BATCH 2
#define ROWS (BATCH*SEQ)   // 4096

typedef __bf16 bf16x8 __attribute__((ext_vector_type(8)));
typedef float  f32x4  __attribute__((ext_vector_type(4)));

__device__ __forceinline__ unsigned short f2b(float f) {
    unsigned int u = __builtin_bit_cast(unsigned int, f);
    u += 0x7fffu + ((u >> 16) & 1u);   // RNE to bf16
    return (unsigned short)(u >> 16);
}
__device__ __forceinline__ float b2f(unsigned short u) {
    return __builtin_bit_cast(float, (unsigned int)u << 16);
}

// async global->LDS, 16B per lane. LDS dest is wave-uniform base + lane*16.
__device__ __forceinline__ void gl_lds16(const unsigned short* g, unsigned short* l) {
    __builtin_amdgcn_global_load_lds(
        (const __attribute__((address_space(1))) unsigned int*)(const void*)g,
        (__attribute__((address_space(3))) unsigned int*)(void*)l, 16, 0, 0);
}

// ---------------- prep: f32 -> bf16 ----------------
__global__ __launch_bounds__(256) void k_f32_to_bf16(const float* __restrict__ in,
                                                     unsigned short* __restrict__ out, int n4) {
    int i = blockIdx.x * 256 + threadIdx.x;
    if (i < n4) {
        float4 v = ((const float4*)in)[i];
        ushort4 u;
        u.x = f2b(v.x); u.y = f2b(v.y); u.z = f2b(v.z); u.w = f2b(v.w);
        ((ushort4*)out)[i] = u;
    }
}

// ---------------- prep: W[R][C] f32 -> WT[C][R] bf16 ----------------
__global__ __launch_bounds__(256) void k_transpose_bf16(const float* __restrict__ W,
                                                        unsigned short* __restrict__ WT,
                                                        int R, int C) {
    __shared__ float t[32][33];
    int c0 = blockIdx.x * 32, r0 = blockIdx.y * 32;
    int tx = threadIdx.x, ty = threadIdx.y;
#pragma unroll
    for (int i = 0; i < 4; i++) {
        int r = ty + i * 8;
        t[r][tx] = W[(size_t)(r0 + r) * C + c0 + tx];
    }
    __syncthreads();
#pragma unroll
    for (int i = 0; i < 4; i++) {
        int r = ty + i * 8;             // output row within tile => column c0+r of W
        WT[(size_t)(c0 + r) * R + r0 + tx] = f2b(t[tx][r]);
    }
}

// ---------------- GEMM: C[M][N] = act(A[M][K] @ BT[N][K]^T + bias) ----------------
// A, BT bf16 row-major. 128x128 tile, BK=64, 4 waves (2x2), 16x16x32 bf16 MFMA.
// m97 structure: global_load_lds width-16 staging, 2 barriers per K-step.
// LDS XOR-swizzle on 16B granules achieved by PRE-SWIZZLING the global source
// (linear LDS dest required by global_load_lds); reads apply the same XOR.
template<bool OUTF32, bool RELU, bool BIASROW>
__global__ __launch_bounds__(256) void k_gemm_bt(const unsigned short* __restrict__ A,
                                                 const unsigned short* __restrict__ BT,
                                                 const float* __restrict__ bias,
                                                 void* __restrict__ Cout,
                                                 int M, int N, int K) {
    __shared__ unsigned short As[128][64] __attribute__((aligned(16)));
    __shared__ unsigned short Bs[128][64] __attribute__((aligned(16)));
    int tid = threadIdx.x;
    int w = tid >> 6, l = tid & 63;
    int wr = w >> 1, wc = w & 1;
    int l15 = l & 15, lg = l >> 4;
    int m0 = blockIdx.y * 128, n0 = blockIdx.x * 128;

    // staging geometry: wave w covers rows w*32 .. w*32+31, 4 instrs of 8 rows.
    int lr8 = l >> 3;                   // row within 8-row chunk
    int gsrc = (l & 7) ^ lr8;           // involution granule swizzle (row&7 == lr8)
    const unsigned short* Abase = A  + (size_t)(m0 + w * 32 + lr8) * K + gsrc * 8;
    const unsigned short* Bbase = BT + (size_t)(n0 + w * 32 + lr8) * K + gsrc * 8;

    f32x4 acc[4][4] = {};

    int nk = K >> 6;
    for (int kt = 0; kt < nk; ++kt) {
        __syncthreads();
#pragma unroll
        for (int it = 0; it < 4; ++it) {
            gl_lds16(Abase + (size_t)(it * 8) * K + kt * 64, &As[w * 32 + it * 8][0]);
            gl_lds16(Bbase + (size_t)(it * 8) * K + kt * 64, &Bs[w * 32 + it * 8][0]);
        }
        __syncthreads();
#pragma unroll
        for (int ks = 0; ks < 2; ++ks) {
            int glog = ks * 4 + lg;
            bf16x8 af[4], bfr[4];
#pragma unroll
            for (int mt = 0; mt < 4; ++mt) {
                int row = wr * 64 + mt * 16 + l15;
                af[mt] = *(const bf16x8*)&As[row][(glog ^ (row & 7)) << 3];
            }
#pragma unroll
            for (int nt = 0; nt < 4; ++nt) {
                int row = wc * 64 + nt * 16 + l15;
                bfr[nt] = *(const bf16x8*)&Bs[row][(glog ^ (row & 7)) << 3];
            }
#pragma unroll
            for (int mt = 0; mt < 4; ++mt)
#pragma unroll
                for (int nt = 0; nt < 4; ++nt)
                    acc[mt][nt] = __builtin_amdgcn_mfma_f32_16x16x32_bf16(af[mt], bfr[nt], acc[mt][nt], 0, 0, 0);
        }
    }
    // epilogue: C/D layout col = lane&15, row = 4*(lane>>4)+r  [m89]
    float browv[4][4];
    if (BIASROW) {
#pragma unroll
        for (int mt = 0; mt < 4; ++mt)
#pragma unroll
            for (int r = 0; r < 4; ++r)
                browv[mt][r] = bias[m0 + wr * 64 + mt * 16 + lg * 4 + r];
    }
#pragma unroll
    for (int nt = 0; nt < 4; ++nt) {
        int col = n0 + wc * 64 + nt * 16 + l15;
        float bv = BIASROW ? 0.f : bias[col];
#pragma unroll
        for (int mt = 0; mt < 4; ++mt) {
#pragma unroll
            for (int r = 0; r < 4; ++r) {
                int row = m0 + wr * 64 + mt * 16 + lg * 4 + r;
                float v = acc[mt][nt][r] + (BIASROW ? browv[mt][r] : bv);
                if (RELU) v = fmaxf(v, 0.f);
                if (OUTF32) ((float*)Cout)[(size_t)row * N + col] = v;
                else        ((unsigned short*)Cout)[(size_t)row * N + col] = f2b(v);
            }
        }
    }
}

// ---------------- flash attention ----------------
// grid flattened+XCD-swizzled, block = 256 (4 waves), each wave owns 16 q-rows.
// K (b,s,h*64+d) stride DM; VT (h*64+d, b*SEQ+s) stride ROWS (from V-proj GEMM).
// Staging: global_load_lds direct to LDS double buffer, pre-swizzled source,
// ONE barrier per key-tile (issue kt+1 -> buf[cur^1]; compute buf[cur]; barrier).
// Softmax: deferred l-sum (per-lane partials, one butterfly at end) + defer-max THR=8.
__global__ __launch_bounds__(256) void k_attn(const unsigned short* __restrict__ Q,
                                              const unsigned short* __restrict__ Kb,
                                              const unsigned short* __restrict__ VT,
                                              unsigned short* __restrict__ O) {
    __shared__ unsigned short ks[2][64][64] __attribute__((aligned(16)));
    __shared__ unsigned short vs[2][64][64] __attribute__((aligned(16)));
    __shared__ unsigned short ps[4][16 * 64] __attribute__((aligned(16)));

    int tid = threadIdx.x;
    int w = tid >> 6, l = tid & 63;
    int l15 = l & 15, lg = l >> 4;

    // bijective XCD swizzle: the 32 q-blocks sharing one (b,h) K/V slab land on one XCD
    int bid = blockIdx.y * gridDim.x + blockIdx.x;          // 0..1023
    int bh = (bid & 7) * 4 + ((bid >> 3) & 3);              // 8 XCDs x 4 bh each
    int qt = bid >> 5;                                      // 0..31
    int b = bh >> 4, h = bh & 15;
    int row0 = qt * 64;

    const unsigned short* qg  = Q  + (size_t)b * SEQ * DM + h * DKH;
    const unsigned short* kg  = Kb + (size_t)b * SEQ * DM + h * DKH;
    const unsigned short* vtg = VT + (size_t)(h * DKH) * ROWS + (size_t)b * SEQ;

    // staging geometry: wave w covers rows w*16 .. w*16+15, 2 instrs of 8 rows
    int lr8 = l >> 3;
    int gsrc = (l & 7) ^ lr8;          // involution granule swizzle

    // issue tile 0
#pragma unroll
    for (int it = 0; it < 2; ++it) {
        int row = w * 16 + it * 8 + lr8;
        gl_lds16(kg + (size_t)row * DM + gsrc * 8,   &ks[0][w * 16 + it * 8][0]);
        gl_lds16(vtg + (size_t)row * ROWS + gsrc * 8, &vs[0][w * 16 + it * 8][0]);
    }

    // Q fragment, pre-scaled by 1/sqrt(dk) = 0.125 (exact pow-2 scale in bf16)
    bf16x8 aq[2];
    {
        int qrow = row0 + w * 16 + l15;
#pragma unroll
        for (int ksi = 0; ksi < 2; ksi++) {
            bf16x8 v = *(const bf16x8*)(qg + (size_t)qrow * DM + (ksi * 4 + lg) * 8);
            const unsigned short* pu = (const unsigned short*)&v;
            bf16x8 rsc;
            unsigned short* pr = (unsigned short*)&rsc;
#pragma unroll
            for (int j = 0; j < 8; j++) pr[j] = f2b(b2f(pu[j]) * 0.125f);
            aq[ksi] = rsc;
        }
    }

    f32x4 o[4] = {};
    float mrun[4], plsum[4];
#pragma unroll
    for (int r = 0; r < 4; r++) { mrun[r] = -__builtin_inff(); plsum[r] = 0.f; }

    unsigned short* pw = ps[w];

    __syncthreads();   // vmcnt drained by barrier: tile 0 ready

    int cur = 0;
    for (int kt = 0; kt < SEQ / 64; ++kt) {
        // issue loads for tile kt+1 into buf[cur^1] (safe: consumed pre-barrier last iter)
        if (kt + 1 < SEQ / 64) {
#pragma unroll
            for (int it = 0; it < 2; ++it) {
                int row = w * 16 + it * 8 + lr8;
                gl_lds16(kg + (size_t)((kt + 1) * 64 + row) * DM + gsrc * 8,
                         &ks[cur ^ 1][w * 16 + it * 8][0]);
                gl_lds16(vtg + (size_t)row * ROWS + (kt + 1) * 64 + gsrc * 8,
                         &vs[cur ^ 1][w * 16 + it * 8][0]);
            }
        }

        // S = (q/8) @ k^T   (16 rows x 64 keys per wave)
        f32x4 s[4] = {};
        __builtin_amdgcn_s_setprio(1);
#pragma unroll
        for (int ksi = 0; ksi < 2; ksi++) {
            int glog = ksi * 4 + lg;
#pragma unroll
            for (int nt = 0; nt < 4; nt++) {
                int row = nt * 16 + l15;
                bf16x8 bk = *(const bf16x8*)&ks[cur][row][(glog ^ (row & 7)) << 3];
                s[nt] = __builtin_amdgcn_mfma_f32_16x16x32_bf16(aq[ksi], bk, s[nt], 0, 0, 0);
            }
        }
        __builtin_amdgcn_s_setprio(0);

        // row-max for this tile: rows = 4*lg + r, keys spread over nt and 16 lanes
        float mt_[4];
#pragma unroll
        for (int r = 0; r < 4; r++)
            mt_[r] = fmaxf(fmaxf(s[0][r], s[1][r]), fmaxf(s[2][r], s[3][r]));
#pragma unroll
        for (int msk = 1; msk < 16; msk <<= 1)
#pragma unroll
            for (int r = 0; r < 4; r++) mt_[r] = fmaxf(mt_[r], __shfl_xor(mt_[r], msk));

        int okl = 1;
#pragma unroll
        for (int r = 0; r < 4; r++) okl &= (mt_[r] <= mrun[r] + 8.f) ? 1 : 0;

        float p[4][4];
        if (__all(okl)) {
            // defer-max: keep old mrun, P bounded by e^8; no O/lsum rescale
            float psum[4] = {0.f, 0.f, 0.f, 0.f};
#pragma unroll
            for (int nt = 0; nt < 4; nt++)
#pragma unroll
                for (int r = 0; r < 4; r++) {
                    float pv_ = __expf(s[nt][r] - mrun[r]);
                    p[nt][r] = pv_;
                    psum[r] += pv_;
                }
#pragma unroll
            for (int r = 0; r < 4; r++) plsum[r] += psum[r];
        } else {
            float al[4], psum[4];
#pragma unroll
            for (int r = 0; r < 4; r++) {
                float nm = fmaxf(mrun[r], mt_[r]);
                al[r] = __expf(mrun[r] - nm);
                mrun[r] = nm;
                psum[r] = 0.f;
            }
#pragma unroll
            for (int nt = 0; nt < 4; nt++)
#pragma unroll
                for (int r = 0; r < 4; r++) {
                    float pv_ = __expf(s[nt][r] - mrun[r]);
                    p[nt][r] = pv_;
                    psum[r] += pv_;
                }
#pragma unroll
            for (int r = 0; r < 4; r++) plsum[r] = plsum[r] * al[r] + psum[r];
#pragma unroll
            for (int nt = 0; nt < 4; nt++)
#pragma unroll
                for (int r = 0; r < 4; r++) o[nt][r] *= al[r];
        }

        // write P (wave-private region, swizzled), then read back as MFMA A-frag
#pragma unroll
        for (int nt = 0; nt < 4; nt++)
#pragma unroll
            for (int r = 0; r < 4; r++) {
                int R = lg * 4 + r;
                int c = nt * 16 + l15;
                pw[R * 64 + (((c >> 3) ^ (R & 7)) << 3) + (c & 7)] = f2b(p[nt][r]);
            }
        asm volatile("s_waitcnt lgkmcnt(0)" ::: "memory");

        // O += P @ V
        __builtin_amdgcn_s_setprio(1);
#pragma unroll
        for (int ksi = 0; ksi < 2; ksi++) {
            int glog = ksi * 4 + lg;
            bf16x8 ap = *(const bf16x8*)&pw[l15 * 64 + ((glog ^ (l15 & 7)) << 3)];
#pragma unroll
            for (int nt = 0; nt < 4; nt++) {
                int row = nt * 16 + l15;   // row = d
                bf16x8 bv = *(const bf16x8*)&vs[cur][row][(glog ^ (row & 7)) << 3];
                o[nt] = __builtin_amdgcn_mfma_f32_16x16x32_bf16(ap, bv, o[nt], 0, 0, 0);
            }
        }
        __builtin_amdgcn_s_setprio(0);

        __syncthreads();   // drains vmcnt (tile kt+1 staged) + all reads of buf[cur] done
        cur ^= 1;
    }

    // final l-sum reduction (deferred butterfly) and output
#pragma unroll
    for (int msk = 1; msk < 16; msk <<= 1)
#pragma unroll
        for (int r = 0; r < 4; r++) plsum[r] += __shfl_xor(plsum[r], msk);
    float rinv[4];
#pragma unroll
    for (int r = 0; r < 4; r++) rinv[r] = 1.f / plsum[r];
    unsigned short* og = O + (size_t)b * SEQ * DM + h * DKH;
#pragma unroll
    for (int nt = 0; nt < 4; nt++) {
        int d = nt * 16 + l15;
#pragma unroll
        for (int r = 0; r < 4; r++) {
            int srow_ = row0 + w * 16 + lg * 4 + r;
            og[(size_t)srow_ * DM + d] = f2b(o[nt][r] * rinv[r]);
        }
    }
}

// ---------------- fused residual add + LayerNorm ----------------
template<bool WB16>
__global__ __launch_bounds__(256) void k_add_ln(const float* __restrict__ a,
                                                const float* __restrict__ b,
                                                const float* __restrict__ gamma,
                                                const float* __restrict__ beta,
                                                float* __restrict__ outf,
                                                unsigned short* __restrict__ outb) {
    __shared__ float red[8];
    int row = blockIdx.x, tid = threadIdx.x;
    float4 va = ((const float4*)(a + (size_t)row * DM))[tid];
    float4 vb = ((const float4*)(b + (size_t)row * DM))[tid];
    float4 v;
    v.x = va.x + vb.x; v.y = va.y + vb.y; v.z = va.z + vb.z; v.w = va.w + vb.w;
    float s = v.x + v.y + v.z + v.w;
    float q = v.x * v.x + v.y * v.y + v.z * v.z + v.w * v.w;
#pragma unroll
    for (int m = 1; m < 64; m <<= 1) { s += __shfl_xor(s, m); q += __shfl_xor(q, m); }
    if ((tid & 63) == 0) { red[tid >> 6] = s; red[4 + (tid >> 6)] = q; }
    __syncthreads();
    float tot  = red[0] + red[1] + red[2] + red[3];
    float totq = red[4] + red[5] + red[6] + red[7];
    float mu = tot * (1.f / DM);
    float var = totq * (1.f / DM) - mu * mu;
    float rs = rsqrtf(var + 1e-5f);
    float4 g  = ((const float4*)gamma)[tid];
    float4 be = ((const float4*)beta)[tid];
    float4 y;
    y.x = (v.x - mu) * rs * g.x + be.x;
    y.y = (v.y - mu) * rs * g.y + be.y;
    y.z = (v.z - mu) * rs * g.z + be.z;
    y.w = (v.w - mu) * rs * g.w + be.w;
    ((float4*)(outf + (size_t)row * DM))[tid] = y;
    if (WB16) {
        ushort4 u;
        u.x = f2b(y.x); u.y = f2b(y.y); u.z = f2b(y.z); u.w = f2b(y.w);
        ((ushort4*)(outb + (size_t)row * DM))[tid] = u;
    }
}

// ---------------- orchestration ----------------
extern "C" void kernel_launch(void* const* d_in, const int* in_sizes, int n_in,
                              void* d_out, int out_size, void* d_ws, size_t ws_size,
                              hipStream_t stream) {
    const float* x   = (const float*)d_in[0];
    const float* Wq  = (const float*)d_in[1];
    const float* bq  = (const float*)d_in[2];
    const float* Wk  = (const float*)d_in[3];
    const float* bk  = (const float*)d_in[4];
    const float* Wv  = (const float*)d_in[5];
    const float* bv  = (const float*)d_in[6];
    const float* Wo  = (const float*)d_in[7];
    const float* bo  = (const float*)d_in[8];
    const float* W1  = (const float*)d_in[9];
    const float* b1  = (const float*)d_in[10];
    const float* W2  = (const float*)d_in[11];
    const float* b2  = (const float*)d_in[12];
    const float* g1  = (const float*)d_in[13];
    const float* be1 = (const float*)d_in[14];
    const float* g2  = (const float*)d_in[15];
    const float* be2 = (const float*)d_in[16];

    char* ws = (char*)d_ws;
    const size_t MB = 1u << 20;
    unsigned short* xb    = (unsigned short*)(ws + 0);        // 8MB; reused as attn_out
    unsigned short* WqT   = (unsigned short*)(ws + 8 * MB);   // 2MB each
    unsigned short* WkT   = (unsigned short*)(ws + 10 * MB);
    unsigned short* WvT   = (unsigned short*)(ws + 12 * MB);
    unsigned short* WoT   = (unsigned short*)(ws + 14 * MB);
    unsigned short* W1T   = (unsigned short*)(ws + 16 * MB);  // 8MB
    unsigned short* W2T   = (unsigned short*)(ws + 24 * MB);  // 8MB
    unsigned short* qb    = (unsigned short*)(ws + 32 * MB);  // 8MB
    unsigned short* kb    = (unsigned short*)(ws + 40 * MB);  // 8MB
    unsigned short* vT    = (unsigned short*)(ws + 48 * MB);  // 8MB: V^T (d_all, b*S+s)
    float*          scrf  = (float*)(ws + 56 * MB);           // 16MB: attn_proj, then ff2
    float*          resid = (float*)(ws + 72 * MB);           // 16MB
    unsigned short* residb= (unsigned short*)(ws + 88 * MB);  // 8MB
    unsigned short* h1    = (unsigned short*)(ws + 96 * MB);  // 32MB

    dim3 blk(256);
    dim3 tb(32, 8);

    k_f32_to_bf16<<<(ROWS * DM / 4 + 255) / 256, blk, 0, stream>>>(x, xb, ROWS * DM / 4);
    k_transpose_bf16<<<dim3(DM / 32, DM / 32), tb, 0, stream>>>(Wq, WqT, DM, DM);
    k_transpose_bf16<<<dim3(DM / 32, DM / 32), tb, 0, stream>>>(Wk, WkT, DM, DM);
    k_transpose_bf16<<<dim3(DM / 32, DM / 32), tb, 0, stream>>>(Wv, WvT, DM, DM);
    k_transpose_bf16<<<dim3(DM / 32, DM / 32), tb, 0, stream>>>(Wo, WoT, DM, DM);
    k_transpose_bf16<<<dim3(DFF / 32, DM / 32), tb, 0, stream>>>(W1, W1T, DM, DFF);
    k_transpose_bf16<<<dim3(DM / 32, DFF / 32), tb, 0, stream>>>(W2, W2T, DFF, DM);

    k_gemm_bt<false, false, false><<<dim3(DM / 128, ROWS / 128), blk, 0, stream>>>(xb, WqT, bq, qb, ROWS, DM, DM);
    k_gemm_bt<false, false, false><<<dim3(DM / 128, ROWS / 128), blk, 0, stream>>>(xb, WkT, bk, kb, ROWS, DM, DM);
    // V^T = WvT @ xb^T  (C[d_all][b*S+s] = (x@Wv+bv)^T), bias per output row
    k_gemm_bt<false, false, true><<<dim3(ROWS / 128, DM / 128), blk, 0, stream>>>(WvT, xb, bv, vT, DM, ROWS, DM);

    k_attn<<<dim3(SEQ / 64, BATCH * NH), blk, 0, stream>>>(qb, kb, vT, xb);

    k_gemm_bt<true, false, false><<<dim3(DM / 128, ROWS / 128), blk, 0, stream>>>(xb, WoT, bo, scrf, ROWS, DM, DM);
    k_add_ln<true><<<ROWS, blk, 0, stream>>>(x, scrf, g1, be1, resid, residb);

    k_gemm_bt<false, true, false><<<dim3(DFF / 128, ROWS / 128), blk, 0, stream>>>(residb, W1T, b1, h1, ROWS, DFF, DM);
    k_gemm_bt<true, false, false><<<dim3(DM / 128, ROWS / 128), blk, 0, stream>>>(h1, W2T, b2, scrf, ROWS, DM, DFF);
    k_add_ln<false><<<ROWS, blk, 0, stream>>>(resid, scrf, g2, be2, (float*)d_out, nullptr);
}

// Round 4
// 324.082 us; speedup vs baseline: 1.6642x; 1.1274x over previous
//
#include <hip/hip_runtime.h>

#define DM   1024
#define DFF  4096
#define NH   16
#define DKH  64
#define SEQ  2048
#define BATCH 2
#define ROWS (BATCH*SEQ)   // 4096

typedef __bf16 bf16x8 __attribute__((ext_vector_type(8)));
typedef float  f32x4  __attribute__((ext_vector_type(4)));

__device__ __forceinline__ unsigned short f2b(float f) {
    unsigned int u = __builtin_bit_cast(unsigned int, f);
    u += 0x7fffu + ((u >> 16) & 1u);   // RNE to bf16
    return (unsigned short)(u >> 16);
}
__device__ __forceinline__ float b2f(unsigned short u) {
    return __builtin_bit_cast(float, (unsigned int)u << 16);
}

// async global->LDS, 16B per lane. LDS dest is wave-uniform base + lane*16.
__device__ __forceinline__ void gl_lds16(const unsigned short* g, unsigned short* l) {
    __builtin_amdgcn_global_load_lds(
        (const __attribute__((address_space(1))) unsigned int*)(const void*)g,
        (__attribute__((address_space(3))) unsigned int*)(void*)l, 16, 0, 0);
}

// ---------------- prep: f32 -> bf16 ----------------
__global__ __launch_bounds__(256) void k_f32_to_bf16(const float* __restrict__ in,
                                                     unsigned short* __restrict__ out, int n4) {
    int i = blockIdx.x * 256 + threadIdx.x;
    if (i < n4) {
        float4 v = ((const float4*)in)[i];
        ushort4 u;
        u.x = f2b(v.x); u.y = f2b(v.y); u.z = f2b(v.z); u.w = f2b(v.w);
        ((ushort4*)out)[i] = u;
    }
}

// ---------------- prep: W[R][C] f32 -> WT[C][R] bf16 ----------------
__global__ __launch_bounds__(256) void k_transpose_bf16(const float* __restrict__ W,
                                                        unsigned short* __restrict__ WT,
                                                        int R, int C) {
    __shared__ float t[32][33];
    int c0 = blockIdx.x * 32, r0 = blockIdx.y * 32;
    int tx = threadIdx.x, ty = threadIdx.y;
#pragma unroll
    for (int i = 0; i < 4; i++) {
        int r = ty + i * 8;
        t[r][tx] = W[(size_t)(r0 + r) * C + c0 + tx];
    }
    __syncthreads();
#pragma unroll
    for (int i = 0; i < 4; i++) {
        int r = ty + i * 8;             // output row within tile => column c0+r of W
        WT[(size_t)(c0 + r) * R + r0 + tx] = f2b(t[tx][r]);
    }
}

// ---------------- GEMM: C[M][N] = act(A[M][K] @ BT[N][K]^T + bias) ----------------
// A, BT bf16 row-major. 128x128 tile, BK=64, 4 waves (2x2), 16x16x32 bf16 MFMA.
// m97 structure: global_load_lds width-16 staging, 2 barriers per K-step.
// LDS XOR-swizzle on 16B granules achieved by PRE-SWIZZLING the global source.
template<bool OUTF32, bool RELU, bool BIASROW>
__global__ __launch_bounds__(256) void k_gemm_bt(const unsigned short* __restrict__ A,
                                                 const unsigned short* __restrict__ BT,
                                                 const float* __restrict__ bias,
                                                 void* __restrict__ Cout,
                                                 int M, int N, int K) {
    __shared__ unsigned short As[128][64] __attribute__((aligned(16)));
    __shared__ unsigned short Bs[128][64] __attribute__((aligned(16)));
    int tid = threadIdx.x;
    int w = tid >> 6, l = tid & 63;
    int wr = w >> 1, wc = w & 1;
    int l15 = l & 15, lg = l >> 4;
    int m0 = blockIdx.y * 128, n0 = blockIdx.x * 128;

    // staging geometry: wave w covers rows w*32 .. w*32+31, 4 instrs of 8 rows.
    int lr8 = l >> 3;                   // row within 8-row chunk
    int gsrc = (l & 7) ^ lr8;           // involution granule swizzle (row&7 == lr8)
    const unsigned short* Abase = A  + (size_t)(m0 + w * 32 + lr8) * K + gsrc * 8;
    const unsigned short* Bbase = BT + (size_t)(n0 + w * 32 + lr8) * K + gsrc * 8;

    f32x4 acc[4][4] = {};

    int nk = K >> 6;
    for (int kt = 0; kt < nk; ++kt) {
        __syncthreads();
#pragma unroll
        for (int it = 0; it < 4; ++it) {
            gl_lds16(Abase + (size_t)(it * 8) * K + kt * 64, &As[w * 32 + it * 8][0]);
            gl_lds16(Bbase + (size_t)(it * 8) * K + kt * 64, &Bs[w * 32 + it * 8][0]);
        }
        __syncthreads();
#pragma unroll
        for (int ks = 0; ks < 2; ++ks) {
            int glog = ks * 4 + lg;
            bf16x8 af[4], bfr[4];
#pragma unroll
            for (int mt = 0; mt < 4; ++mt) {
                int row = wr * 64 + mt * 16 + l15;
                af[mt] = *(const bf16x8*)&As[row][(glog ^ (row & 7)) << 3];
            }
#pragma unroll
            for (int nt = 0; nt < 4; ++nt) {
                int row = wc * 64 + nt * 16 + l15;
                bfr[nt] = *(const bf16x8*)&Bs[row][(glog ^ (row & 7)) << 3];
            }
#pragma unroll
            for (int mt = 0; mt < 4; ++mt)
#pragma unroll
                for (int nt = 0; nt < 4; ++nt)
                    acc[mt][nt] = __builtin_amdgcn_mfma_f32_16x16x32_bf16(af[mt], bfr[nt], acc[mt][nt], 0, 0, 0);
        }
    }
    // epilogue: C/D layout col = lane&15, row = 4*(lane>>4)+r  [m89]
    float browv[4][4];
    if (BIASROW) {
#pragma unroll
        for (int mt = 0; mt < 4; ++mt)
#pragma unroll
            for (int r = 0; r < 4; ++r)
                browv[mt][r] = bias[m0 + wr * 64 + mt * 16 + lg * 4 + r];
    }
#pragma unroll
    for (int nt = 0; nt < 4; ++nt) {
        int col = n0 + wc * 64 + nt * 16 + l15;
        float bv = BIASROW ? 0.f : bias[col];
#pragma unroll
        for (int mt = 0; mt < 4; ++mt) {
#pragma unroll
            for (int r = 0; r < 4; ++r) {
                int row = m0 + wr * 64 + mt * 16 + lg * 4 + r;
                float v = acc[mt][nt][r] + (BIASROW ? browv[mt][r] : bv);
                if (RELU) v = fmaxf(v, 0.f);
                if (OUTF32) ((float*)Cout)[(size_t)row * N + col] = v;
                else        ((unsigned short*)Cout)[(size_t)row * N + col] = f2b(v);
            }
        }
    }
}

// ---------------- flash attention (swapped-QK^T, register-resident P) ----------------
// grid flattened+XCD-swizzled, block = 256 (4 waves), each wave owns 16 q-rows.
// K (b,s,h*64+d) stride DM; VT (h*64+d, b*SEQ+s) stride ROWS (from V-proj GEMM).
// QK^T computed SWAPPED: s[nt] = mfma(K-frag, Q-frag) -> S^T layout: lane holds
// S[q = lane&15][key = nt*16 + lg*4 + r]. Softmax state is scalar per lane.
// PV uses a key-permutation kappa consistent on P (packed locally, no LDS) and V
// (two ds_read_b64 per fragment): kappa(ksi,lg,j) = 32*ksi + 16*(j>>2) + lg*4 + (j&3).
__global__ __launch_bounds__(256) void k_attn(const unsigned short* __restrict__ Q,
                                              const unsigned short* __restrict__ Kb,
                                              const unsigned short* __restrict__ VT,
                                              unsigned short* __restrict__ O) {
    __shared__ unsigned short ks[2][64][64] __attribute__((aligned(16)));
    __shared__ unsigned short vs[2][64][64] __attribute__((aligned(16)));

    int tid = threadIdx.x;
    int w = tid >> 6, l = tid & 63;
    int l15 = l & 15, lg = l >> 4;

    // bijective XCD swizzle: the 32 q-blocks sharing one (b,h) K/V slab land on one XCD
    int bid = blockIdx.y * gridDim.x + blockIdx.x;          // 0..1023
    int bh = (bid & 7) * 4 + ((bid >> 3) & 3);              // 8 XCDs x 4 bh each
    int qt = bid >> 5;                                      // 0..31
    int b = bh >> 4, h = bh & 15;
    int row0 = qt * 64;

    const unsigned short* qg  = Q  + (size_t)b * SEQ * DM + h * DKH;
    const unsigned short* kg  = Kb + (size_t)b * SEQ * DM + h * DKH;
    const unsigned short* vtg = VT + (size_t)(h * DKH) * ROWS + (size_t)b * SEQ;

    // staging geometry: wave w covers rows w*16 .. w*16+15, 2 instrs of 8 rows
    int lr8 = l >> 3;
    int gsrc = (l & 7) ^ lr8;          // involution granule swizzle

    // issue tile 0
#pragma unroll
    for (int it = 0; it < 2; ++it) {
        int row = w * 16 + it * 8 + lr8;
        gl_lds16(kg + (size_t)row * DM + gsrc * 8,    &ks[0][w * 16 + it * 8][0]);
        gl_lds16(vtg + (size_t)row * ROWS + gsrc * 8, &vs[0][w * 16 + it * 8][0]);
    }

    // Q fragment, pre-scaled by 1/sqrt(dk) = 0.125 (exact pow-2 scale in bf16)
    bf16x8 aq[2];
    {
        int qrow = row0 + w * 16 + l15;
#pragma unroll
        for (int ksi = 0; ksi < 2; ksi++) {
            bf16x8 v = *(const bf16x8*)(qg + (size_t)qrow * DM + (ksi * 4 + lg) * 8);
            const unsigned short* pu = (const unsigned short*)&v;
            bf16x8 rsc;
            unsigned short* pr = (unsigned short*)&rsc;
#pragma unroll
            for (int j = 0; j < 8; j++) pr[j] = f2b(b2f(pu[j]) * 0.125f);
            aq[ksi] = rsc;
        }
    }

    f32x4 o[4] = {};
    float mrun = -__builtin_inff();
    float plsum = 0.f;                 // per-lane partial (16 keys/tile), q = l15

    __syncthreads();   // tile 0 staged (barrier drains vmcnt)

    int cur = 0;
    for (int kt = 0; kt < SEQ / 64; ++kt) {
        // issue loads for tile kt+1 into buf[cur^1]
        if (kt + 1 < SEQ / 64) {
#pragma unroll
            for (int it = 0; it < 2; ++it) {
                int row = w * 16 + it * 8 + lr8;
                gl_lds16(kg + (size_t)((kt + 1) * 64 + row) * DM + gsrc * 8,
                         &ks[cur ^ 1][w * 16 + it * 8][0]);
                gl_lds16(vtg + (size_t)row * ROWS + (kt + 1) * 64 + gsrc * 8,
                         &vs[cur ^ 1][w * 16 + it * 8][0]);
            }
        }

        // S^T = K @ (q/8)^T : lane holds S[q=l15][key = nt*16 + lg*4 + r] in s[nt][r]
        f32x4 s[4] = {};
        __builtin_amdgcn_s_setprio(1);
#pragma unroll
        for (int ksi = 0; ksi < 2; ksi++) {
            int glog = ksi * 4 + lg;
#pragma unroll
            for (int nt = 0; nt < 4; nt++) {
                int row = nt * 16 + l15;
                bf16x8 bk = *(const bf16x8*)&ks[cur][row][(glog ^ (row & 7)) << 3];
                s[nt] = __builtin_amdgcn_mfma_f32_16x16x32_bf16(bk, aq[ksi], s[nt], 0, 0, 0);
            }
        }
        __builtin_amdgcn_s_setprio(0);

        // row max: 15 local fmax + 2-step butterfly across lg groups
        float mt = fmaxf(fmaxf(fmaxf(s[0][0], s[0][1]), fmaxf(s[0][2], s[0][3])),
                         fmaxf(fmaxf(s[1][0], s[1][1]), fmaxf(s[1][2], s[1][3])));
        mt = fmaxf(mt, fmaxf(fmaxf(fmaxf(s[2][0], s[2][1]), fmaxf(s[2][2], s[2][3])),
                             fmaxf(fmaxf(s[3][0], s[3][1]), fmaxf(s[3][2], s[3][3]))));
        mt = fmaxf(mt, __shfl_xor(mt, 16));
        mt = fmaxf(mt, __shfl_xor(mt, 32));

        if (!__all(mt <= mrun + 8.f)) {
            float nm = fmaxf(mrun, mt);
            float al = __expf(mrun - nm);
            mrun = nm;
            plsum *= al;
            // broadcast alpha for O rows: q_o = lg*4 + r lives at lane l15' = lg*4+r
            float alo[4];
#pragma unroll
            for (int r = 0; r < 4; r++) alo[r] = __shfl(al, (lg << 4) + lg * 4 + r);
#pragma unroll
            for (int nt = 0; nt < 4; nt++)
#pragma unroll
                for (int r = 0; r < 4; r++) o[nt][r] *= alo[r];
        }

        // P = exp(S - m), local partial sum; pack A-frags locally (key perm kappa)
        float p[4][4];
        float psl = 0.f;
#pragma unroll
        for (int nt = 0; nt < 4; nt++)
#pragma unroll
            for (int r = 0; r < 4; r++) {
                float pv_ = __expf(s[nt][r] - mrun);
                p[nt][r] = pv_;
                psl += pv_;
            }
        plsum += psl;

        bf16x8 af[2];
#pragma unroll
        for (int ksi = 0; ksi < 2; ksi++)
#pragma unroll
            for (int j = 0; j < 8; j++)
                af[ksi][j] = (__bf16)p[2 * ksi + (j >> 2)][j & 3];

        // O += P @ V with permuted keys: B-frag = V^T[d][kappa-slices], two b64 reads
        __builtin_amdgcn_s_setprio(1);
#pragma unroll
        for (int ksi = 0; ksi < 2; ksi++) {
            int g0 = ksi * 4 + (lg >> 1);       // granule of keys 32ksi + lg*4
            int sub = (lg & 1) * 4;             // element offset within granule
#pragma unroll
            for (int nt = 0; nt < 4; nt++) {
                int row = nt * 16 + l15;        // d
                union { bf16x8 v; uint2 u2[2]; } bu;
                bu.u2[0] = *(const uint2*)&vs[cur][row][(((g0)     ^ (row & 7)) << 3) + sub];
                bu.u2[1] = *(const uint2*)&vs[cur][row][(((g0 + 2) ^ (row & 7)) << 3) + sub];
                o[nt] = __builtin_amdgcn_mfma_f32_16x16x32_bf16(af[ksi], bu.v, o[nt], 0, 0, 0);
            }
        }
        __builtin_amdgcn_s_setprio(0);

        __syncthreads();   // reads of buf[cur] done; tile kt+1 staged (vmcnt drained)
        cur ^= 1;
    }

    // final l-sum: combine lg groups, then broadcast to O-row mapping
    plsum += __shfl_xor(plsum, 16);
    plsum += __shfl_xor(plsum, 32);
    float rinv = 1.f / plsum;
    float rinvo[4];
#pragma unroll
    for (int r = 0; r < 4; r++) rinvo[r] = __shfl(rinv, (lg << 4) + lg * 4 + r);

    unsigned short* og = O + (size_t)b * SEQ * DM + h * DKH;
#pragma unroll
    for (int nt = 0; nt < 4; nt++) {
        int d = nt * 16 + l15;
#pragma unroll
        for (int r = 0; r < 4; r++) {
            int srow_ = row0 + w * 16 + lg * 4 + r;
            og[(size_t)srow_ * DM + d] = f2b(o[nt][r] * rinvo[r]);
        }
    }
}

// ---------------- fused residual add + LayerNorm ----------------
template<bool WB16>
__global__ __launch_bounds__(256) void k_add_ln(const float* __restrict__ a,
                                                const float* __restrict__ b,
                                                const float* __restrict__ gamma,
                                                const float* __restrict__ beta,
                                                float* __restrict__ outf,
                                                unsigned short* __restrict__ outb) {
    __shared__ float red[8];
    int row = blockIdx.x, tid = threadIdx.x;
    float4 va = ((const float4*)(a + (size_t)row * DM))[tid];
    float4 vb = ((const float4*)(b + (size_t)row * DM))[tid];
    float4 v;
    v.x = va.x + vb.x; v.y = va.y + vb.y; v.z = va.z + vb.z; v.w = va.w + vb.w;
    float s = v.x + v.y + v.z + v.w;
    float q = v.x * v.x + v.y * v.y + v.z * v.z + v.w * v.w;
#pragma unroll
    for (int m = 1; m < 64; m <<= 1) { s += __shfl_xor(s, m); q += __shfl_xor(q, m); }
    if ((tid & 63) == 0) { red[tid >> 6] = s; red[4 + (tid >> 6)] = q; }
    __syncthreads();
    float tot  = red[0] + red[1] + red[2] + red[3];
    float totq = red[4] + red[5] + red[6] + red[7];
    float mu = tot * (1.f / DM);
    float var = totq * (1.f / DM) - mu * mu;
    float rs = rsqrtf(var + 1e-5f);
    float4 g  = ((const float4*)gamma)[tid];
    float4 be = ((const float4*)beta)[tid];
    float4 y;
    y.x = (v.x - mu) * rs * g.x + be.x;
    y.y = (v.y - mu) * rs * g.y + be.y;
    y.z = (v.z - mu) * rs * g.z + be.z;
    y.w = (v.w - mu) * rs * g.w + be.w;
    ((float4*)(outf + (size_t)row * DM))[tid] = y;
    if (WB16) {
        ushort4 u;
        u.x = f2b(y.x); u.y = f2b(y.y); u.z = f2b(y.z); u.w = f2b(y.w);
        ((ushort4*)(outb + (size_t)row * DM))[tid] = u;
    }
}

// ---------------- orchestration ----------------
extern "C" void kernel_launch(void* const* d_in, const int* in_sizes, int n_in,
                              void* d_out, int out_size, void* d_ws, size_t ws_size,
                              hipStream_t stream) {
    const float* x   = (const float*)d_in[0];
    const float* Wq  = (const float*)d_in[1];
    const float* bq  = (const float*)d_in[2];
    const float* Wk  = (const float*)d_in[3];
    const float* bk  = (const float*)d_in[4];
    const float* Wv  = (const float*)d_in[5];
    const float* bv  = (const float*)d_in[6];
    const float* Wo  = (const float*)d_in[7];
    const float* bo  = (const float*)d_in[8];
    const float* W1  = (const float*)d_in[9];
    const float* b1  = (const float*)d_in[10];
    const float* W2  = (const float*)d_in[11];
    const float* b2  = (const float*)d_in[12];
    const float* g1  = (const float*)d_in[13];
    const float* be1 = (const float*)d_in[14];
    const float* g2  = (const float*)d_in[15];
    const float* be2 = (const float*)d_in[16];

    char* ws = (char*)d_ws;
    const size_t MB = 1u << 20;
    unsigned short* xb    = (unsigned short*)(ws + 0);        // 8MB; reused as attn_out
    unsigned short* WqT   = (unsigned short*)(ws + 8 * MB);   // 2MB each
    unsigned short* WkT   = (unsigned short*)(ws + 10 * MB);
    unsigned short* WvT   = (unsigned short*)(ws + 12 * MB);
    unsigned short* WoT   = (unsigned short*)(ws + 14 * MB);
    unsigned short* W1T   = (unsigned short*)(ws + 16 * MB);  // 8MB
    unsigned short* W2T   = (unsigned short*)(ws + 24 * MB);  // 8MB
    unsigned short* qb    = (unsigned short*)(ws + 32 * MB);  // 8MB
    unsigned short* kb    = (unsigned short*)(ws + 40 * MB);  // 8MB
    unsigned short* vT    = (unsigned short*)(ws + 48 * MB);  // 8MB: V^T (d_all, b*S+s)
    float*          scrf  = (float*)(ws + 56 * MB);           // 16MB: attn_proj, then ff2
    float*          resid = (float*)(ws + 72 * MB);           // 16MB
    unsigned short* residb= (unsigned short*)(ws + 88 * MB);  // 8MB
    unsigned short* h1    = (unsigned short*)(ws + 96 * MB);  // 32MB

    dim3 blk(256);
    dim3 tb(32, 8);

    k_f32_to_bf16<<<(ROWS * DM / 4 + 255) / 256, blk, 0, stream>>>(x, xb, ROWS * DM / 4);
    k_transpose_bf16<<<dim3(DM / 32, DM / 32), tb, 0, stream>>>(Wq, WqT, DM, DM);
    k_transpose_bf16<<<dim3(DM / 32, DM / 32), tb, 0, stream>>>(Wk, WkT, DM, DM);
    k_transpose_bf16<<<dim3(DM / 32, DM / 32), tb, 0, stream>>>(Wv, WvT, DM, DM);
    k_transpose_bf16<<<dim3(DM / 32, DM / 32), tb, 0, stream>>>(Wo, WoT, DM, DM);
    k_transpose_bf16<<<dim3(DFF / 32, DM / 32), tb, 0, stream>>>(W1, W1T, DM, DFF);
    k_transpose_bf16<<<dim3(DM / 32, DFF / 32), tb, 0, stream>>>(W2, W2T, DFF, DM);

    k_gemm_bt<false, false, false><<<dim3(DM / 128, ROWS / 128), blk, 0, stream>>>(xb, WqT, bq, qb, ROWS, DM, DM);
    k_gemm_bt<false, false, false><<<dim3(DM / 128, ROWS / 128), blk, 0, stream>>>(xb, WkT, bk, kb, ROWS, DM, DM);
    // V^T = WvT @ xb^T  (C[d_all][b*S+s] = (x@Wv+bv)^T), bias per output row
    k_gemm_bt<false, false, true><<<dim3(ROWS / 128, DM / 128), blk, 0, stream>>>(WvT, xb, bv, vT, DM, ROWS, DM);

    k_attn<<<dim3(SEQ / 64, BATCH * NH), blk, 0, stream>>>(qb, kb, vT, xb);

    k_gemm_bt<true, false, false><<<dim3(DM / 128, ROWS / 128), blk, 0, stream>>>(xb, WoT, bo, scrf, ROWS, DM, DM);
    k_add_ln<true><<<ROWS, blk, 0, stream>>>(x, scrf, g1, be1, resid, residb);

    k_gemm_bt<false, true, false><<<dim3(DFF / 128, ROWS / 128), blk, 0, stream>>>(residb, W1T, b1, h1, ROWS, DFF, DM);
    k_gemm_bt<true, false, false><<<dim3(DM / 128, ROWS / 128), blk, 0, stream>>>(h1, W2T, b2, scrf, ROWS, DM, DFF);
    k_add_ln<false><<<ROWS, blk, 0, stream>>>(resid, scrf, g2, be2, (float*)d_out, nullptr);
}

// Round 5
// 282.800 us; speedup vs baseline: 1.9071x; 1.1460x over previous
//
#include <hip/hip_runtime.h>

#define DM   1024
#define DFF  4096
#define NH   16
#define DKH  64
#define SEQ  2048
#define BATCH 2
#define ROWS (BATCH*SEQ)   // 4096

typedef __bf16 bf16x8 __attribute__((ext_vector_type(8)));
typedef float  f32x4  __attribute__((ext_vector_type(4)));

__device__ __forceinline__ unsigned short f2b(float f) {
    unsigned int u = __builtin_bit_cast(unsigned int, f);
    u += 0x7fffu + ((u >> 16) & 1u);   // RNE to bf16
    return (unsigned short)(u >> 16);
}
__device__ __forceinline__ float b2f(unsigned short u) {
    return __builtin_bit_cast(float, (unsigned int)u << 16);
}

// async global->LDS, 16B per lane. LDS dest is wave-uniform base + lane*16.
__device__ __forceinline__ void gl_lds16(const unsigned short* g, unsigned short* l) {
    __builtin_amdgcn_global_load_lds(
        (const __attribute__((address_space(1))) unsigned int*)(const void*)g,
        (__attribute__((address_space(3))) unsigned int*)(void*)l, 16, 0, 0);
}

// ---------------- prep: f32 -> bf16 ----------------
__global__ __launch_bounds__(256) void k_f32_to_bf16(const float* __restrict__ in,
                                                     unsigned short* __restrict__ out, int n4) {
    int i = blockIdx.x * 256 + threadIdx.x;
    if (i < n4) {
        float4 v = ((const float4*)in)[i];
        ushort4 u;
        u.x = f2b(v.x); u.y = f2b(v.y); u.z = f2b(v.z); u.w = f2b(v.w);
        ((ushort4*)out)[i] = u;
    }
}

// ---------------- prep: W[R][C] f32 -> WT[C][R] bf16 ----------------
__global__ __launch_bounds__(256) void k_transpose_bf16(const float* __restrict__ W,
                                                        unsigned short* __restrict__ WT,
                                                        int R, int C) {
    __shared__ float t[32][33];
    int c0 = blockIdx.x * 32, r0 = blockIdx.y * 32;
    int tx = threadIdx.x, ty = threadIdx.y;
#pragma unroll
    for (int i = 0; i < 4; i++) {
        int r = ty + i * 8;
        t[r][tx] = W[(size_t)(r0 + r) * C + c0 + tx];
    }
    __syncthreads();
#pragma unroll
    for (int i = 0; i < 4; i++) {
        int r = ty + i * 8;             // output row within tile => column c0+r of W
        WT[(size_t)(c0 + r) * R + r0 + tx] = f2b(t[tx][r]);
    }
}

// ---------------- GEMM: C[M][N] = act(A[M][K] @ BT[N][K]^T + bias) ----------------
// A, BT bf16 row-major. Block tile (2*WM)x(2*WN), BK=64, 4 waves (2x2), each wave WMxWN.
// m97 structure: global_load_lds width-16 staging, 2 barriers per K-step.
// LDS XOR-swizzle on 16B granules achieved by PRE-SWIZZLING the global source.
// Chunked bijective XCD swizzle (requires nwg % 8 == 0) for A-panel L2 locality.
template<int WM, int WN, bool OUTF32, bool RELU, bool BIASROW>
__global__ __launch_bounds__(256) void k_gemm_bt(const unsigned short* __restrict__ A,
                                                 const unsigned short* __restrict__ BT,
                                                 const float* __restrict__ bias,
                                                 void* __restrict__ Cout,
                                                 int M, int N, int K) {
    constexpr int BM = 2 * WM, BN = 2 * WN;
    constexpr int MT = WM / 16, NT = WN / 16;
    constexpr int IA = BM / 32, IB = BN / 32;   // gl_lds16 instrs per wave (8 rows each)
    __shared__ unsigned short As[BM][64] __attribute__((aligned(16)));
    __shared__ unsigned short Bs[BN][64] __attribute__((aligned(16)));
    int tid = threadIdx.x;
    int w = tid >> 6, l = tid & 63;
    int wr = w >> 1, wc = w & 1;
    int l15 = l & 15, lg = l >> 4;

    // XCD swizzle: contiguous work chunks per XCD
    int bid = blockIdx.y * gridDim.x + blockIdx.x;
    int nwg = gridDim.x * gridDim.y;
    int swz = (bid & 7) * (nwg >> 3) + (bid >> 3);
    int m0 = (swz / gridDim.x) * BM, n0 = (swz % gridDim.x) * BN;

    // staging geometry: wave w covers BM/4 (BN/4) rows, IA (IB) instrs of 8 rows.
    int lr8 = l >> 3;                   // row within 8-row chunk
    int gsrc = (l & 7) ^ lr8;           // involution granule swizzle (row&7 == lr8)
    const unsigned short* Abase = A  + (size_t)(m0 + w * (BM / 4) + lr8) * K + gsrc * 8;
    const unsigned short* Bbase = BT + (size_t)(n0 + w * (BN / 4) + lr8) * K + gsrc * 8;

    f32x4 acc[MT][NT] = {};

    int nk = K >> 6;
    for (int kt = 0; kt < nk; ++kt) {
        __syncthreads();
#pragma unroll
        for (int it = 0; it < IA; ++it)
            gl_lds16(Abase + (size_t)(it * 8) * K + kt * 64, &As[w * (BM / 4) + it * 8][0]);
#pragma unroll
        for (int it = 0; it < IB; ++it)
            gl_lds16(Bbase + (size_t)(it * 8) * K + kt * 64, &Bs[w * (BN / 4) + it * 8][0]);
        __syncthreads();
#pragma unroll
        for (int ks = 0; ks < 2; ++ks) {
            int glog = ks * 4 + lg;
            bf16x8 af[MT], bfr[NT];
#pragma unroll
            for (int mt = 0; mt < MT; ++mt) {
                int row = wr * WM + mt * 16 + l15;
                af[mt] = *(const bf16x8*)&As[row][(glog ^ (row & 7)) << 3];
            }
#pragma unroll
            for (int nt = 0; nt < NT; ++nt) {
                int row = wc * WN + nt * 16 + l15;
                bfr[nt] = *(const bf16x8*)&Bs[row][(glog ^ (row & 7)) << 3];
            }
#pragma unroll
            for (int mt = 0; mt < MT; ++mt)
#pragma unroll
                for (int nt = 0; nt < NT; ++nt)
                    acc[mt][nt] = __builtin_amdgcn_mfma_f32_16x16x32_bf16(af[mt], bfr[nt], acc[mt][nt], 0, 0, 0);
        }
    }
    // epilogue: C/D layout col = lane&15, row = 4*(lane>>4)+r  [m89]
    float browv[MT][4];
    if (BIASROW) {
#pragma unroll
        for (int mt = 0; mt < MT; ++mt)
#pragma unroll
            for (int r = 0; r < 4; ++r)
                browv[mt][r] = bias[m0 + wr * WM + mt * 16 + lg * 4 + r];
    }
#pragma unroll
    for (int nt = 0; nt < NT; ++nt) {
        int col = n0 + wc * WN + nt * 16 + l15;
        float bv = BIASROW ? 0.f : bias[col];
#pragma unroll
        for (int mt = 0; mt < MT; ++mt) {
#pragma unroll
            for (int r = 0; r < 4; ++r) {
                int row = m0 + wr * WM + mt * 16 + lg * 4 + r;
                float v = acc[mt][nt][r] + (BIASROW ? browv[mt][r] : bv);
                if (RELU) v = fmaxf(v, 0.f);
                if (OUTF32) ((float*)Cout)[(size_t)row * N + col] = v;
                else        ((unsigned short*)Cout)[(size_t)row * N + col] = f2b(v);
            }
        }
    }
}

// ---------------- flash attention (swapped-QK^T, register-resident P) ----------------
// grid flattened+XCD-swizzled, block = 256 (4 waves), each wave owns 16 q-rows.
// K (b,s,h*64+d) stride DM; VT (h*64+d, b*SEQ+s) stride ROWS (from V-proj GEMM).
// QK^T computed SWAPPED: s[nt] = mfma(K-frag, Q-frag) -> S^T layout: lane holds
// S[q = lane&15][key = nt*16 + lg*4 + r]. Softmax state is scalar per lane.
// PV uses a key-permutation kappa consistent on P (packed locally, no LDS) and V
// (two ds_read_b64 per fragment): kappa(ksi,lg,j) = 32*ksi + 16*(j>>2) + lg*4 + (j&3).
__global__ __launch_bounds__(256) void k_attn(const unsigned short* __restrict__ Q,
                                              const unsigned short* __restrict__ Kb,
                                              const unsigned short* __restrict__ VT,
                                              unsigned short* __restrict__ O) {
    __shared__ unsigned short ks[2][64][64] __attribute__((aligned(16)));
    __shared__ unsigned short vs[2][64][64] __attribute__((aligned(16)));

    int tid = threadIdx.x;
    int w = tid >> 6, l = tid & 63;
    int l15 = l & 15, lg = l >> 4;

    // bijective XCD swizzle: the 32 q-blocks sharing one (b,h) K/V slab land on one XCD
    int bid = blockIdx.y * gridDim.x + blockIdx.x;          // 0..1023
    int bh = (bid & 7) * 4 + ((bid >> 3) & 3);              // 8 XCDs x 4 bh each
    int qt = bid >> 5;                                      // 0..31
    int b = bh >> 4, h = bh & 15;
    int row0 = qt * 64;

    const unsigned short* qg  = Q  + (size_t)b * SEQ * DM + h * DKH;
    const unsigned short* kg  = Kb + (size_t)b * SEQ * DM + h * DKH;
    const unsigned short* vtg = VT + (size_t)(h * DKH) * ROWS + (size_t)b * SEQ;

    // staging geometry: wave w covers rows w*16 .. w*16+15, 2 instrs of 8 rows
    int lr8 = l >> 3;
    int gsrc = (l & 7) ^ lr8;          // involution granule swizzle

    // issue tile 0
#pragma unroll
    for (int it = 0; it < 2; ++it) {
        int row = w * 16 + it * 8 + lr8;
        gl_lds16(kg + (size_t)row * DM + gsrc * 8,    &ks[0][w * 16 + it * 8][0]);
        gl_lds16(vtg + (size_t)row * ROWS + gsrc * 8, &vs[0][w * 16 + it * 8][0]);
    }

    // Q fragment, pre-scaled by 1/sqrt(dk) = 0.125 (exact pow-2 scale in bf16)
    bf16x8 aq[2];
    {
        int qrow = row0 + w * 16 + l15;
#pragma unroll
        for (int ksi = 0; ksi < 2; ksi++) {
            bf16x8 v = *(const bf16x8*)(qg + (size_t)qrow * DM + (ksi * 4 + lg) * 8);
            const unsigned short* pu = (const unsigned short*)&v;
            bf16x8 rsc;
            unsigned short* pr = (unsigned short*)&rsc;
#pragma unroll
            for (int j = 0; j < 8; j++) pr[j] = f2b(b2f(pu[j]) * 0.125f);
            aq[ksi] = rsc;
        }
    }

    f32x4 o[4] = {};
    float mrun = -__builtin_inff();
    float plsum = 0.f;                 // per-lane partial (16 keys/tile), q = l15

    __syncthreads();   // tile 0 staged (barrier drains vmcnt)

    int cur = 0;
    for (int kt = 0; kt < SEQ / 64; ++kt) {
        // issue loads for tile kt+1 into buf[cur^1]
        if (kt + 1 < SEQ / 64) {
#pragma unroll
            for (int it = 0; it < 2; ++it) {
                int row = w * 16 + it * 8 + lr8;
                gl_lds16(kg + (size_t)((kt + 1) * 64 + row) * DM + gsrc * 8,
                         &ks[cur ^ 1][w * 16 + it * 8][0]);
                gl_lds16(vtg + (size_t)row * ROWS + (kt + 1) * 64 + gsrc * 8,
                         &vs[cur ^ 1][w * 16 + it * 8][0]);
            }
        }

        // S^T = K @ (q/8)^T : lane holds S[q=l15][key = nt*16 + lg*4 + r] in s[nt][r]
        f32x4 s[4] = {};
        __builtin_amdgcn_s_setprio(1);
#pragma unroll
        for (int ksi = 0; ksi < 2; ksi++) {
            int glog = ksi * 4 + lg;
#pragma unroll
            for (int nt = 0; nt < 4; nt++) {
                int row = nt * 16 + l15;
                bf16x8 bk = *(const bf16x8*)&ks[cur][row][(glog ^ (row & 7)) << 3];
                s[nt] = __builtin_amdgcn_mfma_f32_16x16x32_bf16(bk, aq[ksi], s[nt], 0, 0, 0);
            }
        }
        __builtin_amdgcn_s_setprio(0);

        // row max: 15 local fmax + 2-step butterfly across lg groups
        float mt = fmaxf(fmaxf(fmaxf(s[0][0], s[0][1]), fmaxf(s[0][2], s[0][3])),
                         fmaxf(fmaxf(s[1][0], s[1][1]), fmaxf(s[1][2], s[1][3])));
        mt = fmaxf(mt, fmaxf(fmaxf(fmaxf(s[2][0], s[2][1]), fmaxf(s[2][2], s[2][3])),
                             fmaxf(fmaxf(s[3][0], s[3][1]), fmaxf(s[3][2], s[3][3]))));
        mt = fmaxf(mt, __shfl_xor(mt, 16));
        mt = fmaxf(mt, __shfl_xor(mt, 32));

        if (!__all(mt <= mrun + 8.f)) {
            float nm = fmaxf(mrun, mt);
            float al = __expf(mrun - nm);
            mrun = nm;
            plsum *= al;
            // broadcast alpha for O rows: q_o = lg*4 + r lives at lane l15' = lg*4+r
            float alo[4];
#pragma unroll
            for (int r = 0; r < 4; r++) alo[r] = __shfl(al, (lg << 4) + lg * 4 + r);
#pragma unroll
            for (int nt = 0; nt < 4; nt++)
#pragma unroll
                for (int r = 0; r < 4; r++) o[nt][r] *= alo[r];
        }

        // P = exp(S - m), local partial sum; pack A-frags locally (key perm kappa)
        float p[4][4];
        float psl = 0.f;
#pragma unroll
        for (int nt = 0; nt < 4; nt++)
#pragma unroll
            for (int r = 0; r < 4; r++) {
                float pv_ = __expf(s[nt][r] - mrun);
                p[nt][r] = pv_;
                psl += pv_;
            }
        plsum += psl;

        bf16x8 af[2];
#pragma unroll
        for (int ksi = 0; ksi < 2; ksi++)
#pragma unroll
            for (int j = 0; j < 8; j++)
                af[ksi][j] = (__bf16)p[2 * ksi + (j >> 2)][j & 3];

        // O += P @ V with permuted keys: B-frag = V^T[d][kappa-slices], two b64 reads
        __builtin_amdgcn_s_setprio(1);
#pragma unroll
        for (int ksi = 0; ksi < 2; ksi++) {
            int g0 = ksi * 4 + (lg >> 1);       // granule of keys 32ksi + lg*4
            int sub = (lg & 1) * 4;             // element offset within granule
#pragma unroll
            for (int nt = 0; nt < 4; nt++) {
                int row = nt * 16 + l15;        // d
                union { bf16x8 v; uint2 u2[2]; } bu;
                bu.u2[0] = *(const uint2*)&vs[cur][row][(((g0)     ^ (row & 7)) << 3) + sub];
                bu.u2[1] = *(const uint2*)&vs[cur][row][(((g0 + 2) ^ (row & 7)) << 3) + sub];
                o[nt] = __builtin_amdgcn_mfma_f32_16x16x32_bf16(af[ksi], bu.v, o[nt], 0, 0, 0);
            }
        }
        __builtin_amdgcn_s_setprio(0);

        __syncthreads();   // reads of buf[cur] done; tile kt+1 staged (vmcnt drained)
        cur ^= 1;
    }

    // final l-sum: combine lg groups, then broadcast to O-row mapping
    plsum += __shfl_xor(plsum, 16);
    plsum += __shfl_xor(plsum, 32);
    float rinv = 1.f / plsum;
    float rinvo[4];
#pragma unroll
    for (int r = 0; r < 4; r++) rinvo[r] = __shfl(rinv, (lg << 4) + lg * 4 + r);

    unsigned short* og = O + (size_t)b * SEQ * DM + h * DKH;
#pragma unroll
    for (int nt = 0; nt < 4; nt++) {
        int d = nt * 16 + l15;
#pragma unroll
        for (int r = 0; r < 4; r++) {
            int srow_ = row0 + w * 16 + lg * 4 + r;
            og[(size_t)srow_ * DM + d] = f2b(o[nt][r] * rinvo[r]);
        }
    }
}

// ---------------- fused residual add + LayerNorm ----------------
template<bool WB16>
__global__ __launch_bounds__(256) void k_add_ln(const float* __restrict__ a,
                                                const float* __restrict__ b,
                                                const float* __restrict__ gamma,
                                                const float* __restrict__ beta,
                                                float* __restrict__ outf,
                                                unsigned short* __restrict__ outb) {
    __shared__ float red[8];
    int row = blockIdx.x, tid = threadIdx.x;
    float4 va = ((const float4*)(a + (size_t)row * DM))[tid];
    float4 vb = ((const float4*)(b + (size_t)row * DM))[tid];
    float4 v;
    v.x = va.x + vb.x; v.y = va.y + vb.y; v.z = va.z + vb.z; v.w = va.w + vb.w;
    float s = v.x + v.y + v.z + v.w;
    float q = v.x * v.x + v.y * v.y + v.z * v.z + v.w * v.w;
#pragma unroll
    for (int m = 1; m < 64; m <<= 1) { s += __shfl_xor(s, m); q += __shfl_xor(q, m); }
    if ((tid & 63) == 0) { red[tid >> 6] = s; red[4 + (tid >> 6)] = q; }
    __syncthreads();
    float tot  = red[0] + red[1] + red[2] + red[3];
    float totq = red[4] + red[5] + red[6] + red[7];
    float mu = tot * (1.f / DM);
    float var = totq * (1.f / DM) - mu * mu;
    float rs = rsqrtf(var + 1e-5f);
    float4 g  = ((const float4*)gamma)[tid];
    float4 be = ((const float4*)beta)[tid];
    float4 y;
    y.x = (v.x - mu) * rs * g.x + be.x;
    y.y = (v.y - mu) * rs * g.y + be.y;
    y.z = (v.z - mu) * rs * g.z + be.z;
    y.w = (v.w - mu) * rs * g.w + be.w;
    ((float4*)(outf + (size_t)row * DM))[tid] = y;
    if (WB16) {
        ushort4 u;
        u.x = f2b(y.x); u.y = f2b(y.y); u.z = f2b(y.z); u.w = f2b(y.w);
        ((ushort4*)(outb + (size_t)row * DM))[tid] = u;
    }
}

// ---------------- orchestration ----------------
extern "C" void kernel_launch(void* const* d_in, const int* in_sizes, int n_in,
                              void* d_out, int out_size, void* d_ws, size_t ws_size,
                              hipStream_t stream) {
    const float* x   = (const float*)d_in[0];
    const float* Wq  = (const float*)d_in[1];
    const float* bq  = (const float*)d_in[2];
    const float* Wk  = (const float*)d_in[3];
    const float* bk  = (const float*)d_in[4];
    const float* Wv  = (const float*)d_in[5];
    const float* bv  = (const float*)d_in[6];
    const float* Wo  = (const float*)d_in[7];
    const float* bo  = (const float*)d_in[8];
    const float* W1  = (const float*)d_in[9];
    const float* b1  = (const float*)d_in[10];
    const float* W2  = (const float*)d_in[11];
    const float* b2  = (const float*)d_in[12];
    const float* g1  = (const float*)d_in[13];
    const float* be1 = (const float*)d_in[14];
    const float* g2  = (const float*)d_in[15];
    const float* be2 = (const float*)d_in[16];

    char* ws = (char*)d_ws;
    const size_t MB = 1u << 20;
    unsigned short* xb    = (unsigned short*)(ws + 0);        // 8MB; reused as attn_out
    unsigned short* WqT   = (unsigned short*)(ws + 8 * MB);   // 2MB each
    unsigned short* WkT   = (unsigned short*)(ws + 10 * MB);
    unsigned short* WvT   = (unsigned short*)(ws + 12 * MB);
    unsigned short* WoT   = (unsigned short*)(ws + 14 * MB);
    unsigned short* W1T   = (unsigned short*)(ws + 16 * MB);  // 8MB
    unsigned short* W2T   = (unsigned short*)(ws + 24 * MB);  // 8MB
    unsigned short* qb    = (unsigned short*)(ws + 32 * MB);  // 8MB
    unsigned short* kb    = (unsigned short*)(ws + 40 * MB);  // 8MB
    unsigned short* vT    = (unsigned short*)(ws + 48 * MB);  // 8MB: V^T (d_all, b*S+s)
    float*          scrf  = (float*)(ws + 56 * MB);           // 16MB: attn_proj, then ff2
    float*          resid = (float*)(ws + 72 * MB);           // 16MB
    unsigned short* residb= (unsigned short*)(ws + 88 * MB);  // 8MB
    unsigned short* h1    = (unsigned short*)(ws + 96 * MB);  // 32MB

    dim3 blk(256);
    dim3 tb(32, 8);

    k_f32_to_bf16<<<(ROWS * DM / 4 + 255) / 256, blk, 0, stream>>>(x, xb, ROWS * DM / 4);
    k_transpose_bf16<<<dim3(DM / 32, DM / 32), tb, 0, stream>>>(Wq, WqT, DM, DM);
    k_transpose_bf16<<<dim3(DM / 32, DM / 32), tb, 0, stream>>>(Wk, WkT, DM, DM);
    k_transpose_bf16<<<dim3(DM / 32, DM / 32), tb, 0, stream>>>(Wv, WvT, DM, DM);
    k_transpose_bf16<<<dim3(DM / 32, DM / 32), tb, 0, stream>>>(Wo, WoT, DM, DM);
    k_transpose_bf16<<<dim3(DFF / 32, DM / 32), tb, 0, stream>>>(W1, W1T, DM, DFF);
    k_transpose_bf16<<<dim3(DM / 32, DFF / 32), tb, 0, stream>>>(W2, W2T, DFF, DM);

    // N=1024 projections: 64x128 tiles -> 512 blocks = 2 blocks/CU
    k_gemm_bt<32, 64, false, false, false><<<dim3(DM / 128, ROWS / 64), blk, 0, stream>>>(xb, WqT, bq, qb, ROWS, DM, DM);
    k_gemm_bt<32, 64, false, false, false><<<dim3(DM / 128, ROWS / 64), blk, 0, stream>>>(xb, WkT, bk, kb, ROWS, DM, DM);
    // V^T = WvT @ xb^T  (C[d_all][b*S+s] = (x@Wv+bv)^T), bias per output row
    k_gemm_bt<32, 64, false, false, true><<<dim3(ROWS / 128, DM / 64), blk, 0, stream>>>(WvT, xb, bv, vT, DM, ROWS, DM);

    k_attn<<<dim3(SEQ / 64, BATCH * NH), blk, 0, stream>>>(qb, kb, vT, xb);

    k_gemm_bt<32, 64, true, false, false><<<dim3(DM / 128, ROWS / 64), blk, 0, stream>>>(xb, WoT, bo, scrf, ROWS, DM, DM);
    k_add_ln<true><<<ROWS, blk, 0, stream>>>(x, scrf, g1, be1, resid, residb);

    // FF1: N=4096 -> 128x128 tiles, 1024 blocks = 4 blocks/CU
    k_gemm_bt<64, 64, false, true, false><<<dim3(DFF / 128, ROWS / 128), blk, 0, stream>>>(residb, W1T, b1, h1, ROWS, DFF, DM);
    // FF2: N=1024 -> 64x128 tiles, 512 blocks = 2 blocks/CU
    k_gemm_bt<32, 64, true, false, false><<<dim3(DM / 128, ROWS / 64), blk, 0, stream>>>(h1, W2T, b2, scrf, ROWS, DM, DFF);
    k_add_ln<false><<<ROWS, blk, 0, stream>>>(resid, scrf, g2, be2, (float*)d_out, nullptr);
}